// Round 5
// baseline (438.264 us; speedup 1.0000x reference)
//
#include <hip/hip_runtime.h>

// ---------- types ----------
typedef __attribute__((ext_vector_type(8))) short short8;   // 8 x bf16
typedef __attribute__((ext_vector_type(4))) short short4v;  // 4 x bf16
typedef __attribute__((ext_vector_type(2))) int int2v;
typedef __attribute__((ext_vector_type(4))) float float4v;

#define MFMA16(a, b, c) __builtin_amdgcn_mfma_f32_16x16x32_bf16((a), (b), (c), 0, 0, 0)

__device__ __forceinline__ short f2bf(float f) {  // RNE fp32 -> bf16
  unsigned u = __float_as_uint(f);
  u += 0x7fffu + ((u >> 16) & 1u);
  return (short)(u >> 16);
}

// packed fp32x2 -> bf16x2 (RNE) in one VALU op
__device__ __forceinline__ int cvtpk(float a, float b) {
  int r;
  asm("v_cvt_pk_bf16_f32 %0, %1, %2" : "=v"(r) : "v"(a), "v"(b));
  return r;
}

// async global->LDS, 16B per lane; LDS dest = wave-uniform base + lane*16
__device__ __forceinline__ void glds16(const short* g, short* l) {
  __builtin_amdgcn_global_load_lds(
      (const __attribute__((address_space(1))) void*)g,
      (__attribute__((address_space(3))) void*)l, 16, 0, 0);
}

// ---------- fused fp32 -> bf16 cast (all 9 tensors, one launch) ----------
struct CastSeg { const float* src; short* dst; int n4; };
struct CastArgs { CastSeg seg[9]; int start[10]; };

__global__ __launch_bounds__(256) void castk(CastArgs a) {
  int blk = blockIdx.x;
  int si = 0;
#pragma unroll
  for (int i = 1; i < 9; i++) si += (blk >= a.start[i]);
  int i = (blk - a.start[si]) * 256 + threadIdx.x;
  if (i >= a.seg[si].n4) return;
  float4v f = ((const float4v*)a.seg[si].src)[i];
  short4v o;
  o[0] = f2bf(f[0]); o[1] = f2bf(f[1]); o[2] = f2bf(f[2]); o[3] = f2bf(f[3]);
  ((short4v*)a.seg[si].dst)[i] = o;
}

// ---------- segmented runtime-flag MFMA GEMM ----------
// Template BK = K-step (32 or 64). BK=32 halves LDS (32KB/block) -> 4
// blocks/CU for fat-K GEMMs (latency hiding via TLP). BK=64 keeps the
// thin-K (K=128) single-barrier fast path + V^T transpose scratch.
// flags: 1=ROPE, 2=SCALE, 4=V^T out (BK=64 only), 8=fp32 out,
//        16=bn-pair (two 128-col tiles per block, K=128/BK=64 only)
struct GSeg {
  const short* A;
  const short* W;
  const float* bias0;
  const float* bias1;
  void* outp;
  int lda, ldw, bsplit, ropestart, ldo, ocol, K, flags;
};
struct GArgs { GSeg s[3]; int start[4]; };

template <int TAG, int BK>
__global__ __launch_bounds__(256, 2) void gemm_rt(GArgs ga, const int* __restrict__ pos) {
  constexpr int LPR = BK / 8;    // lanes per 64/128B row within one glds16
  constexpr int RPG = 64 / LPR;  // rows per glds16
  constexpr int NJ = LPR / 2;    // glds16 per wave per operand per buffer
  constexpr int KS = BK / 32;    // 32-deep MFMA steps per K-step
  int by = blockIdx.y;
  int si = (by >= ga.start[1]) + (by >= ga.start[2]);
  const GSeg sg = ga.s[si];
  int tid = threadIdx.x, w = tid >> 6, lane = tid & 63;
  int quad = lane >> 4, l16 = lane & 15;
  bool ropeF = sg.flags & 1, scaleF = sg.flags & 2;
  bool vtF = sg.flags & 4, f32F = sg.flags & 8, pairF = sg.flags & 16;
  int bm = blockIdx.x * 128;
  int bn = (by - ga.start[si]) * (pairF ? 256 : 128);
  int wm = (w & 1) * 64, wn = (w >> 1) * 64;
  int lda = sg.lda, ldw = sg.ldw;

  __shared__ short At[2][128 * BK];
  __shared__ short Bt[2][128 * BK];

  int srow[NJ], soff[NJ];
#pragma unroll
  for (int j = 0; j < NJ; j++) {
    int r = w * 32 + j * RPG + (lane / LPR);
    srow[j] = r;
    soff[j] = ((lane & (LPR - 1)) ^ (r & (LPR - 1))) << 3;
  }
  const short* Ag = sg.A + (size_t)bm * lda;
  const short* Wg = sg.W + (size_t)bn * ldw;

  float4v acc[4][4];
  float4v z = {0.f, 0.f, 0.f, 0.f};
#pragma unroll
  for (int mi = 0; mi < 4; mi++)
#pragma unroll
    for (int ni = 0; ni < 4; ni++) acc[mi][ni] = z;

  auto stage = [&](const short* g, int ldg, short* dst, int ko) {
#pragma unroll
    for (int j = 0; j < NJ; j++)
      glds16(g + (size_t)srow[j] * ldg + ko + soff[j], dst + (w * 32 + j * RPG) * BK);
  };

  auto comp = [&](const short* Ab, const short* Bb) {
#pragma unroll
    for (int ks = 0; ks < KS; ks++) {
      short8 af[4], bf[4];
#pragma unroll
      for (int mi = 0; mi < 4; mi++) {
        int row = wm + mi * 16 + l16;
        af[mi] = *(const short8*)&Ab[row * BK +
                                     ((((ks << 2) + quad) ^ (row & (LPR - 1))) << 3)];
      }
#pragma unroll
      for (int ni = 0; ni < 4; ni++) {
        int row = wn + ni * 16 + l16;
        bf[ni] = *(const short8*)&Bb[row * BK +
                                     ((((ks << 2) + quad) ^ (row & (LPR - 1))) << 3)];
      }
#pragma unroll
      for (int mi = 0; mi < 4; mi++)
#pragma unroll
        for (int ni = 0; ni < 4; ni++)
          acc[mi][ni] = MFMA16(af[mi], bf[ni], acc[mi][ni]);
    }
  };

  // ---- epilogue (runtime flags; block-uniform branches) ----
  auto epi = [&](int bnX) {
    if (vtF) {  // only reachable in BK=64 instantiations (launcher guarantees)
      __syncthreads();  // all waves done reading At/Bt
      short* T = &At[0][0];
#pragma unroll
      for (int ni = 0; ni < 4; ni++) {
        int col = wn + ni * 16 + l16;
        float bv = sg.bias0[bnX + col];
#pragma unroll
        for (int mi = 0; mi < 4; mi++) {
          int row0 = wm + mi * 16 + quad * 4;
          int rr = (row0 + ((col & 15) << 3)) & 127;
          short4v ov;
#pragma unroll
          for (int r = 0; r < 4; r++) ov[r] = f2bf(acc[mi][ni][r] + bv);
          *(short4v*)&T[col * 128 + rr] = ov;
        }
      }
      __syncthreads();
      int bidx = bm >> 11, s0 = bm & 2047;
      int sc = tid & 15;
#pragma unroll
      for (int cc = 0; cc < 8; cc++) {
        int c = cc * 16 + (tid >> 4);
        int rr = ((sc + (c & 15)) << 3) & 127;
        short8 v = *(const short8*)&T[c * 128 + rr];
        *(short8*)((short*)sg.outp + ((size_t)(bidx * 1536 + bnX + c)) * 2048 +
                   s0 + (sc << 3)) = v;
      }
      return;
    }
#pragma unroll
    for (int ni = 0; ni < 4; ni++) {
      int col = bnX + wn + ni * 16 + l16;
      float bv = (col < sg.bsplit) ? sg.bias0[col] : sg.bias1[col - sg.bsplit];
      float fr = 0.f;
      bool dorope = ropeF && (col >= sg.ropestart);
      if (dorope) {
        int ri = (col - sg.ropestart) & ~1;
        fr = exp2f((float)ri * (-13.287712379549449f / 768.0f));
      }
#pragma unroll
      for (int mi = 0; mi < 4; mi++) {
        int row0 = bm + wm + mi * 16 + quad * 4;
#pragma unroll
        for (int r = 0; r < 4; r++) {
          int row = row0 + r;
          float v = acc[mi][ni][r] + bv;
          if (ropeF) {
            float pv = __shfl_xor(v, 1, 64);
            if (dorope) {
              float ang = (float)pos[row & 2047] * fr;
              float sn, cs;
              __sincosf(ang, &sn, &cs);
              v = (col & 1) ? (pv * sn + v * cs) : (v * cs - pv * sn);
            }
          }
          if (scaleF) v *= 0.12751743f;  // (1/sqrt(128)) * log2(e)
          if (f32F)
            ((float*)sg.outp)[(size_t)row * sg.ldo + sg.ocol + col] = v;
          else
            ((short*)sg.outp)[(size_t)row * sg.ldo + sg.ocol + col] = f2bf(v);
        }
      }
    }
  };

  int nk = sg.K / BK;
  if constexpr (BK == 64) {
    if (nk == 2) {
      // thin-K fast path: stage K=128 entirely, one barrier
      stage(Ag, lda, At[0], 0);
      stage(Ag, lda, At[1], 64);
      stage(Wg, ldw, Bt[0], 0);
      stage(Wg, ldw, Bt[1], 64);
      __syncthreads();
      comp(At[0], Bt[0]);
      comp(At[1], Bt[1]);
      if (pairF) {
        __syncthreads();
        stage(Wg + (size_t)128 * ldw, ldw, Bt[0], 0);
        stage(Wg + (size_t)128 * ldw, ldw, Bt[1], 64);
        epi(bn);
#pragma unroll
        for (int mi = 0; mi < 4; mi++)
#pragma unroll
          for (int ni = 0; ni < 4; ni++) acc[mi][ni] = z;
        __syncthreads();
        comp(At[0], Bt[0]);
        comp(At[1], Bt[1]);
        epi(bn + 128);
      } else {
        epi(bn);
      }
      return;
    }
  }
  stage(Ag, lda, At[0], 0);
  stage(Wg, ldw, Bt[0], 0);
  for (int it = 0; it < nk; it++) {
    __syncthreads();
    if (it + 1 < nk) {
      int kt = (it + 1) * BK, nb = (it + 1) & 1;
      stage(Ag, lda, At[nb], kt);
      stage(Wg, ldw, Bt[nb], kt);
    }
    comp(At[it & 1], Bt[it & 1]);
  }
  epi(bn);
}

// ---------- causal flash attention: 128-q blocks, 32 q/wave, no-max softmax ----
// grid 768 (1-D, global LPT order), 256 thr. KVBLK=64 (R3-proven; KVBLK=32
// regressed: per-tile latency constant, critical path doubled, conflicts 2.5x).
__global__ __launch_bounds__(256, 2) void mla_attn(const short* __restrict__ Q,
                                                   const short* __restrict__ K,
                                                   const short* __restrict__ Vt,
                                                   short* __restrict__ O) {
  const int ld = 1536, SEQ = 2048;
  int tid = threadIdx.x, w = tid >> 6, lane = tid & 63;
  int quad = lane >> 4, l16 = lane & 15;
  int o = (int)blockIdx.x;
  int rank = o / 48;
  int g = o - rank * 48;
  int qt = (15 - rank) * 128;
  int hh = g % 12, b = g / 12;
  int qw = qt + w * 32;

  __shared__ short Kt[2][64 * 128];
  __shared__ short Vl[2][128 * 64];
  __shared__ short Pm[4][32 * 64];
  char* pwB = (char*)Pm[w];

  int kgo[4], vgo[4];
#pragma unroll
  for (int j = 0; j < 4; j++) {
    int rk = (w * 4 + j) * 4 + (lane >> 4);
    kgo[j] = rk * ld + (((lane & 15) ^ (rk & 7)) << 3);
    int rv = (w * 4 + j) * 8 + (lane >> 3);
    vgo[j] = rv * SEQ + (((lane & 7) ^ (rv & 7)) << 3);
  }
  const short* Kg = K + (size_t)b * SEQ * ld + hh * 128;
  const short* Vg = Vt + (size_t)(b * 12 + hh) * 128 * SEQ;

  short8 qf[2][4];
  {
    const short* Qg = Q + (size_t)(b * SEQ + qw + l16) * ld + hh * 128 + quad * 8;
#pragma unroll
    for (int nf = 0; nf < 2; nf++)
#pragma unroll
      for (int ks = 0; ks < 4; ks++)
        qf[nf][ks] = *(const short8*)(Qg + (size_t)nf * 16 * ld + ks * 32);
  }

  // ---- loop-invariant LDS byte offsets ----
  int koff[4][4], voff[2][8], pfo[2][2], pwo[2][4];
#pragma unroll
  for (int ks = 0; ks < 4; ks++)
#pragma unroll
    for (int mf = 0; mf < 4; mf++) {
      int row = mf * 16 + l16;
      koff[ks][mf] = row * 256 + ((((ks << 2) + quad) ^ (row & 7)) << 4);
    }
#pragma unroll
  for (int t = 0; t < 2; t++) {
#pragma unroll
    for (int df = 0; df < 8; df++) {
      int vr = df * 16 + l16;
      voff[t][df] = vr * 128 + ((((t << 2) + quad) ^ (vr & 7)) << 4);
    }
#pragma unroll
    for (int mq = 0; mq < 2; mq++)
      pfo[t][mq] = (mq * 16 + l16) * 128 + ((((t << 2) + quad) ^ (l16 & 7)) << 4);
#pragma unroll
    for (int mf = 0; mf < 4; mf++) {
      int p = (mf * 2 + (quad >> 1)) ^ (l16 & 7);
      pwo[t][mf] = (t * 16 + l16) * 128 + (p << 4) + ((quad & 1) << 3);
    }
  }

  float4v z = {0.f, 0.f, 0.f, 0.f};
  float4v oacc[2][8];
#pragma unroll
  for (int mq = 0; mq < 2; mq++)
#pragma unroll
    for (int df = 0; df < 8; df++) oacc[mq][df] = z;
  float l_i[2] = {0.f, 0.f};

#pragma unroll
  for (int j = 0; j < 4; j++) glds16(Kg + kgo[j], &Kt[0][(w * 4 + j) * 512]);
#pragma unroll
  for (int j = 0; j < 4; j++) glds16(Vg + vgo[j], &Vl[0][(w * 4 + j) * 512]);

  int ntiles = (qt >> 6) + 2;  // always even

#define ATTN_TILE(IT, NB, NB1)                                                 \
  do {                                                                         \
    int kt = (IT) << 6;                                                        \
    __syncthreads();                                                           \
    if ((IT) + 1 < ntiles) {                                                   \
      const short* kn = Kg + (size_t)(kt + 64) * ld;                           \
      const short* vn = Vg + (kt + 64);                                        \
      _Pragma("unroll") for (int j = 0; j < 4; j++)                            \
          glds16(kn + kgo[j], &Kt[NB1][(w * 4 + j) * 512]);                    \
      _Pragma("unroll") for (int j = 0; j < 4; j++)                            \
          glds16(vn + vgo[j], &Vl[NB1][(w * 4 + j) * 512]);                    \
    }                                                                          \
    if (kt <= qw + 31) {                                                       \
      const char* Kb = (const char*)Kt[NB];                                    \
      const char* Vb = (const char*)Vl[NB];                                    \
      float4v sf[4][2];                                                        \
      __builtin_amdgcn_s_setprio(1);                                           \
      _Pragma("unroll") for (int mf = 0; mf < 4; mf++) {                       \
        short8 a = *(const short8*)(Kb + koff[0][mf]);                         \
        sf[mf][0] = MFMA16(a, qf[0][0], z);                                    \
        sf[mf][1] = MFMA16(a, qf[1][0], z);                                    \
      }                                                                        \
      _Pragma("unroll") for (int ks = 1; ks < 4; ks++) {                       \
        _Pragma("unroll") for (int mf = 0; mf < 4; mf++) {                     \
          short8 a = *(const short8*)(Kb + koff[ks][mf]);                      \
          sf[mf][0] = MFMA16(a, qf[0][ks], sf[mf][0]);                         \
          sf[mf][1] = MFMA16(a, qf[1][ks], sf[mf][1]);                         \
        }                                                                      \
      }                                                                        \
      __builtin_amdgcn_s_setprio(0);                                           \
      if (kt + 63 > qw) {                                                      \
        _Pragma("unroll") for (int mf = 0; mf < 4; mf++) {                     \
          int key = kt + mf * 16 + quad * 4;                                   \
          _Pragma("unroll") for (int nf = 0; nf < 2; nf++) {                   \
            int q = qw + nf * 16 + l16;                                        \
            _Pragma("unroll") for (int r = 0; r < 4; r++)                      \
                if (key + r > q) sf[mf][nf][r] = -3e38f;                       \
          }                                                                    \
        }                                                                      \
      }                                                                        \
      _Pragma("unroll") for (int nf = 0; nf < 2; nf++) {                       \
        float ps = 0.f;                                                        \
        _Pragma("unroll") for (int mf = 0; mf < 4; mf++)                       \
            _Pragma("unroll") for (int r = 0; r < 4; r++) {                    \
          float e = exp2f(sf[mf][nf][r]);                                      \
          sf[mf][nf][r] = e;                                                   \
          ps += e;                                                             \
        }                                                                      \
        l_i[nf] += ps;                                                         \
        _Pragma("unroll") for (int mf = 0; mf < 4; mf++) {                     \
          int2v pk;                                                            \
          pk[0] = cvtpk(sf[mf][nf][0], sf[mf][nf][1]);                         \
          pk[1] = cvtpk(sf[mf][nf][2], sf[mf][nf][3]);                         \
          *(int2v*)(pwB + pwo[nf][mf]) = pk;                                   \
        }                                                                      \
      }                                                                        \
      __builtin_amdgcn_s_setprio(1);                                           \
      _Pragma("unroll") for (int t = 0; t < 2; t++) {                          \
        short8 pf0 = *(const short8*)(pwB + pfo[t][0]);                        \
        short8 pf1 = *(const short8*)(pwB + pfo[t][1]);                        \
        _Pragma("unroll") for (int df = 0; df < 8; df++) {                     \
          short8 vf = *(const short8*)(Vb + voff[t][df]);                      \
          oacc[0][df] = MFMA16(pf0, vf, oacc[0][df]);                          \
          oacc[1][df] = MFMA16(pf1, vf, oacc[1][df]);                          \
        }                                                                      \
      }                                                                        \
      __builtin_amdgcn_s_setprio(0);                                           \
    }                                                                          \
  } while (0)

  for (int it = 0; it < ntiles; it += 2) {
    ATTN_TILE(it, 0, 1);
    ATTN_TILE(it + 1, 1, 0);
  }
#undef ATTN_TILE

  // ---- epilogue: reduce l across quads, scale, store ----
  short* Og = O + (size_t)(b * SEQ + qw) * ld + hh * 128;
#pragma unroll
  for (int mq = 0; mq < 2; mq++) {
    float l = l_i[mq];
    l += __shfl_xor(l, 16, 64);
    l += __shfl_xor(l, 32, 64);
    float linv = 1.0f / l;
    float lb[4];
#pragma unroll
    for (int r = 0; r < 4; r++) lb[r] = __shfl(linv, (quad << 2) + r, 64);
#pragma unroll
    for (int df = 0; df < 8; df++)
#pragma unroll
      for (int r = 0; r < 4; r++)
        Og[(size_t)(mq * 16 + (quad << 2) + r) * ld + df * 16 + l16] =
            f2bf(oacc[mq][df][r] * lb[r]);
  }
}

// ---------- launcher ----------
extern "C" void kernel_launch(void* const* d_in, const int* in_sizes, int n_in,
                              void* d_out, int out_size, void* d_ws, size_t ws_size,
                              hipStream_t stream) {
  const int S = 2048, DM = 768, DL = 128, HD = 1536;
  const int M = 4 * S;  // 8192
  const int BIG = 1 << 28;

  const float* x = (const float*)d_in[0];
  const int* pos = (const int*)d_in[1];
  const float* W_dkv = (const float*)d_in[2];
  const float* b_dkv = (const float*)d_in[3];
  const float* W_dq = (const float*)d_in[4];
  const float* b_dq = (const float*)d_in[5];
  const float* W_uk_nope = (const float*)d_in[6];
  const float* b_uk_nope = (const float*)d_in[7];
  const float* W_uv = (const float*)d_in[8];
  const float* b_uv = (const float*)d_in[9];
  const float* W_uq_nope = (const float*)d_in[10];
  const float* b_uq_nope = (const float*)d_in[11];
  const float* W_uq_rope = (const float*)d_in[12];
  const float* b_uq_rope = (const float*)d_in[13];
  const float* W_uk_rope = (const float*)d_in[14];
  const float* b_uk_rope = (const float*)d_in[15];
  const float* W_o = (const float*)d_in[16];
  const float* b_o = (const float*)d_in[17];

  char* p = (char*)d_ws;
  size_t off = 0;
  auto take = [&](size_t nelem) -> short* {
    short* r = (short*)(p + off);
    off += (nelem * 2 + 255) & ~(size_t)255;
    return r;
  };
  short* xb = take((size_t)M * DM);
  short* Wdq = take(DL * DM);
  short* Wdkv = take(DL * DM);
  short* Wuqnope = take(768 * DL);
  short* Wuqrope = take(768 * DL);
  short* Wuknope = take(768 * DL);
  short* Wuv = take(1536 * DL);
  short* Wukrope = take(768 * DM);
  short* Wo = take(768 * 1536);
  short* Cm = take((size_t)M * 256);  // [C_q | C_kv]
  short* Qm = take((size_t)M * HD);
  short* Km = take((size_t)M * HD);
  short* Vtm = take((size_t)M * HD);  // V^T: [b][h*128+d][s]
  short* Om = take((size_t)M * HD);
  if (off > ws_size) return;

  CastArgs ca;
  const float* srcs[9] = {x, W_dq, W_dkv, W_uq_nope, W_uq_rope, W_uk_nope, W_uv, W_uk_rope, W_o};
  short* dsts[9] = {xb, Wdq, Wdkv, Wuqnope, Wuqrope, Wuknope, Wuv, Wukrope, Wo};
  int ns[9] = {M * DM, DL * DM, DL * DM, 768 * DL, 768 * DL, 768 * DL, 1536 * DL, 768 * DM, 768 * 1536};
  ca.start[0] = 0;
  for (int i = 0; i < 9; i++) {
    ca.seg[i].src = srcs[i];
    ca.seg[i].dst = dsts[i];
    ca.seg[i].n4 = ns[i] / 4;
    ca.start[i + 1] = ca.start[i] + (ca.seg[i].n4 + 255) / 256;
  }
  castk<<<dim3(ca.start[9]), dim3(256), 0, stream>>>(ca);

  // ---- launch 1 (BK=32, 4 blk/CU): C (N=256,K=768) || rope(k_rope) (N=768,K=768) ----
  GArgs g1;
  g1.s[0].A = xb;   g1.s[0].W = Wdq;      g1.s[0].bias0 = b_dq;      g1.s[0].bias1 = b_dkv;
  g1.s[0].outp = Cm; g1.s[0].lda = DM; g1.s[0].ldw = DM; g1.s[0].bsplit = 128;
  g1.s[0].ropestart = 0; g1.s[0].ldo = 256; g1.s[0].ocol = 0; g1.s[0].K = DM; g1.s[0].flags = 0;
  g1.s[1].A = xb;   g1.s[1].W = Wukrope;  g1.s[1].bias0 = b_uk_rope; g1.s[1].bias1 = b_uk_rope;
  g1.s[1].outp = Km; g1.s[1].lda = DM; g1.s[1].ldw = DM; g1.s[1].bsplit = BIG;
  g1.s[1].ropestart = 0; g1.s[1].ldo = HD; g1.s[1].ocol = 768; g1.s[1].K = DM; g1.s[1].flags = 1;
  g1.s[2] = g1.s[1];
  g1.start[0] = 0; g1.start[1] = 2; g1.start[2] = 8; g1.start[3] = 8;
  gemm_rt<1, 32><<<dim3(M / 128, 8), dim3(256), 0, stream>>>(g1, pos);

  // ---- launch 2 (BK=64): Q (paired) || k_nope (paired) || V^T, all K=128 ----
  GArgs g2;
  g2.s[0].A = Cm;   g2.s[0].W = Wuqnope;  g2.s[0].bias0 = b_uq_nope; g2.s[0].bias1 = b_uq_rope;
  g2.s[0].outp = Qm; g2.s[0].lda = 256; g2.s[0].ldw = DL; g2.s[0].bsplit = 768;
  g2.s[0].ropestart = 768; g2.s[0].ldo = HD; g2.s[0].ocol = 0; g2.s[0].K = DL;
  g2.s[0].flags = 1 | 2 | 16;
  g2.s[1].A = Cm + 128; g2.s[1].W = Wuknope; g2.s[1].bias0 = b_uk_nope; g2.s[1].bias1 = b_uk_nope;
  g2.s[1].outp = Km; g2.s[1].lda = 256; g2.s[1].ldw = DL; g2.s[1].bsplit = BIG;
  g2.s[1].ropestart = 0; g2.s[1].ldo = HD; g2.s[1].ocol = 0; g2.s[1].K = DL;
  g2.s[1].flags = 16;
  g2.s[2].A = Cm + 128; g2.s[2].W = Wuv;   g2.s[2].bias0 = b_uv;      g2.s[2].bias1 = b_uv;
  g2.s[2].outp = Vtm; g2.s[2].lda = 256; g2.s[2].ldw = DL; g2.s[2].bsplit = BIG;
  g2.s[2].ropestart = 0; g2.s[2].ldo = 0; g2.s[2].ocol = 0; g2.s[2].K = DL;
  g2.s[2].flags = 4;
  g2.start[0] = 0; g2.start[1] = 6; g2.start[2] = 9; g2.start[3] = 21;
  gemm_rt<2, 64><<<dim3(M / 128, 21), dim3(256), 0, stream>>>(g2, pos);

  // ---- attention: 768 blocks, global longest-first (LPT) order ----
  mla_attn<<<dim3(768), dim3(256), 0, stream>>>(Qm, Km, Vtm, Om);

  // ---- launch 3 (BK=32, 4 blk/CU): out = O @ W_o^T + b_o (N=768, K=1536, fp32) ----
  GArgs g3;
  g3.s[0].A = Om;   g3.s[0].W = Wo;       g3.s[0].bias0 = b_o;       g3.s[0].bias1 = b_o;
  g3.s[0].outp = d_out; g3.s[0].lda = HD; g3.s[0].ldw = HD; g3.s[0].bsplit = BIG;
  g3.s[0].ropestart = 0; g3.s[0].ldo = 768; g3.s[0].ocol = 0; g3.s[0].K = HD; g3.s[0].flags = 8;
  g3.s[1] = g3.s[0];
  g3.s[2] = g3.s[0];
  g3.start[0] = 0; g3.start[1] = 6; g3.start[2] = 6; g3.start[3] = 6;
  gemm_rt<3, 32><<<dim3(M / 128, 6), dim3(256), 0, stream>>>(g3, pos);
}

// Round 6
// 417.295 us; speedup vs baseline: 1.0503x; 1.0503x over previous
//
#include <hip/hip_runtime.h>

// ---------- types ----------
typedef __attribute__((ext_vector_type(8))) short short8;   // 8 x bf16
typedef __attribute__((ext_vector_type(4))) short short4v;  // 4 x bf16
typedef __attribute__((ext_vector_type(2))) int int2v;
typedef __attribute__((ext_vector_type(4))) float float4v;

#define MFMA16(a, b, c) __builtin_amdgcn_mfma_f32_16x16x32_bf16((a), (b), (c), 0, 0, 0)

__device__ __forceinline__ short f2bf(float f) {  // RNE fp32 -> bf16
  unsigned u = __float_as_uint(f);
  u += 0x7fffu + ((u >> 16) & 1u);
  return (short)(u >> 16);
}

// packed fp32x2 -> bf16x2 (RNE) in one VALU op
__device__ __forceinline__ int cvtpk(float a, float b) {
  int r;
  asm("v_cvt_pk_bf16_f32 %0, %1, %2" : "=v"(r) : "v"(a), "v"(b));
  return r;
}

// async global->LDS, 16B per lane; LDS dest = wave-uniform base + lane*16
__device__ __forceinline__ void glds16(const short* g, short* l) {
  __builtin_amdgcn_global_load_lds(
      (const __attribute__((address_space(1))) void*)g,
      (__attribute__((address_space(3))) void*)l, 16, 0, 0);
}

// ---------- fused fp32 -> bf16 cast (all 9 tensors, one launch) ----------
struct CastSeg { const float* src; short* dst; int n4; };
struct CastArgs { CastSeg seg[9]; int start[10]; };

__global__ __launch_bounds__(256) void castk(CastArgs a) {
  int blk = blockIdx.x;
  int si = 0;
#pragma unroll
  for (int i = 1; i < 9; i++) si += (blk >= a.start[i]);
  int i = (blk - a.start[si]) * 256 + threadIdx.x;
  if (i >= a.seg[si].n4) return;
  float4v f = ((const float4v*)a.seg[si].src)[i];
  short4v o;
  o[0] = f2bf(f[0]); o[1] = f2bf(f[1]); o[2] = f2bf(f[2]); o[3] = f2bf(f[3]);
  ((short4v*)a.seg[si].dst)[i] = o;
}

// ---------- segmented runtime-flag MFMA GEMM (BK=64, R3-proven) ----------
// out[m, ocol+n] = A(M,K) @ W(N,K)^T + bias. Block 128x128, 4 waves 2x2.
// Grid: blockIdx.x = m-tile (fastest) -> XCD-pinned m-rows (row operand L2-hit).
// K==128 fast path: stage K entirely, then loop sg.ntile output tiles sharing
// the A stage (B re-staged, DMA overlapped with epilogue where legal).
// flags: 1=ROPE, 2=SCALE, 4=V^T out (LDS-transposed, Bt as scratch), 8=fp32 out
struct GSeg {
  const short* A;
  const short* W;
  const float* bias0;
  const float* bias1;
  void* outp;
  int lda, ldw, bsplit, ropestart, ldo, ocol, K, flags, ntile;
};
struct GArgs { GSeg s[3]; int start[4]; };

template <int TAG>
__global__ __launch_bounds__(256, 2) void gemm_rt(GArgs ga, const int* __restrict__ pos) {
  int by = blockIdx.y;
  int si = (by >= ga.start[1]) + (by >= ga.start[2]);
  const GSeg sg = ga.s[si];
  int tid = threadIdx.x, w = tid >> 6, lane = tid & 63;
  int quad = lane >> 4, l16 = lane & 15;
  bool ropeF = sg.flags & 1, scaleF = sg.flags & 2;
  bool vtF = sg.flags & 4, f32F = sg.flags & 8;
  int bm = blockIdx.x * 128;
  int bn = (by - ga.start[si]) * (128 * sg.ntile);
  int wm = (w & 1) * 64, wn = (w >> 1) * 64;
  int lda = sg.lda, ldw = sg.ldw;

  __shared__ short At[2][128 * 64];
  __shared__ short Bt[2][128 * 64];

  int srow[4], soff[4];
#pragma unroll
  for (int j = 0; j < 4; j++) {
    int r = w * 32 + j * 8 + (lane >> 3);
    srow[j] = r;
    soff[j] = ((lane & 7) ^ (r & 7)) << 3;
  }
  const short* Ag = sg.A + (size_t)bm * lda;
  const short* Wg = sg.W + (size_t)bn * ldw;

  float4v acc[4][4];
  float4v z = {0.f, 0.f, 0.f, 0.f};
#pragma unroll
  for (int mi = 0; mi < 4; mi++)
#pragma unroll
    for (int ni = 0; ni < 4; ni++) acc[mi][ni] = z;

  auto stage = [&](const short* g, int ldg, short* dst, int ko) {
#pragma unroll
    for (int j = 0; j < 4; j++)
      glds16(g + (size_t)srow[j] * ldg + ko + soff[j], dst + (w * 32 + j * 8) * 64);
  };

  auto comp = [&](const short* Ab, const short* Bb) {
#pragma unroll
    for (int ks = 0; ks < 2; ks++) {
      short8 af[4], bf[4];
#pragma unroll
      for (int mi = 0; mi < 4; mi++) {
        int row = wm + mi * 16 + l16;
        af[mi] = *(const short8*)&Ab[(row << 6) + ((((ks << 2) + quad) ^ (row & 7)) << 3)];
      }
#pragma unroll
      for (int ni = 0; ni < 4; ni++) {
        int row = wn + ni * 16 + l16;
        bf[ni] = *(const short8*)&Bb[(row << 6) + ((((ks << 2) + quad) ^ (row & 7)) << 3)];
      }
#pragma unroll
      for (int mi = 0; mi < 4; mi++)
#pragma unroll
        for (int ni = 0; ni < 4; ni++)
          acc[mi][ni] = MFMA16(af[mi], bf[ni], acc[mi][ni]);
    }
  };

  // ---- epilogue (runtime flags; block-uniform branches) ----
  auto epi = [&](int bnX) {
    if (vtF) {
      // transpose 128x128 tile through LDS; scratch = Bt (dead after comp)
      __syncthreads();  // all waves done with comp (Bt reads)
      short* T = &Bt[0][0];  // 32KB contiguous across Bt[0]+Bt[1]
#pragma unroll
      for (int ni = 0; ni < 4; ni++) {
        int col = wn + ni * 16 + l16;
        float bv = sg.bias0[bnX + col];
#pragma unroll
        for (int mi = 0; mi < 4; mi++) {
          int row0 = wm + mi * 16 + quad * 4;
          int rr = (row0 + ((col & 15) << 3)) & 127;
          short4v ov;
#pragma unroll
          for (int r = 0; r < 4; r++) ov[r] = f2bf(acc[mi][ni][r] + bv);
          *(short4v*)&T[col * 128 + rr] = ov;
        }
      }
      __syncthreads();
      int bidx = bm >> 11, s0 = bm & 2047;
      int sc = tid & 15;
#pragma unroll
      for (int cc = 0; cc < 8; cc++) {
        int c = cc * 16 + (tid >> 4);
        int rr = ((sc + (c & 15)) << 3) & 127;
        short8 v = *(const short8*)&T[c * 128 + rr];
        *(short8*)((short*)sg.outp + ((size_t)(bidx * 1536 + bnX + c)) * 2048 +
                   s0 + (sc << 3)) = v;
      }
      return;
    }
#pragma unroll
    for (int ni = 0; ni < 4; ni++) {
      int col = bnX + wn + ni * 16 + l16;
      float bv = (col < sg.bsplit) ? sg.bias0[col] : sg.bias1[col - sg.bsplit];
      float fr = 0.f;
      bool dorope = ropeF && (col >= sg.ropestart);
      if (dorope) {
        int ri = (col - sg.ropestart) & ~1;
        fr = exp2f((float)ri * (-13.287712379549449f / 768.0f));
      }
#pragma unroll
      for (int mi = 0; mi < 4; mi++) {
        int row0 = bm + wm + mi * 16 + quad * 4;
#pragma unroll
        for (int r = 0; r < 4; r++) {
          int row = row0 + r;
          float v = acc[mi][ni][r] + bv;
          if (ropeF) {
            float pv = __shfl_xor(v, 1, 64);
            if (dorope) {
              float ang = (float)pos[row & 2047] * fr;
              float sn, cs;
              __sincosf(ang, &sn, &cs);
              v = (col & 1) ? (pv * sn + v * cs) : (v * cs - pv * sn);
            }
          }
          if (scaleF) v *= 0.12751743f;  // (1/sqrt(128)) * log2(e)
          if (f32F)
            ((float*)sg.outp)[(size_t)row * sg.ldo + sg.ocol + col] = v;
          else
            ((short*)sg.outp)[(size_t)row * sg.ldo + sg.ocol + col] = f2bf(v);
        }
      }
    }
  };

  int nk = sg.K >> 6;
  if (nk == 2) {
    // thin-K fast path: stage A for K=128 once; loop ntile B-tiles
    stage(Ag, lda, At[0], 0);
    stage(Ag, lda, At[1], 64);
    stage(Wg, ldw, Bt[0], 0);
    stage(Wg, ldw, Bt[1], 64);
    __syncthreads();
    comp(At[0], Bt[0]);
    comp(At[1], Bt[1]);
    int nt = sg.ntile;
    for (int t = 1; t < nt; t++) {
      const short* WgT = Wg + (size_t)(t * 128) * ldw;
      __syncthreads();  // all waves done reading Bt
      if (vtF) {
        epi(bn + (t - 1) * 128);  // uses Bt as scratch (internal barriers)
        __syncthreads();          // no wave still reading scratch when DMA lands
        stage(WgT, ldw, Bt[0], 0);
        stage(WgT, ldw, Bt[1], 64);
      } else {
        stage(WgT, ldw, Bt[0], 0);  // DMA overlaps epilogue
        stage(WgT, ldw, Bt[1], 64);
        epi(bn + (t - 1) * 128);
      }
#pragma unroll
      for (int mi = 0; mi < 4; mi++)
#pragma unroll
        for (int ni = 0; ni < 4; ni++) acc[mi][ni] = z;
      __syncthreads();  // drains glds16
      comp(At[0], Bt[0]);
      comp(At[1], Bt[1]);
    }
    epi(bn + (nt - 1) * 128);
    return;
  }
  // fat-K double-buffered loop (BK=64)
  stage(Ag, lda, At[0], 0);
  stage(Wg, ldw, Bt[0], 0);
  for (int it = 0; it < nk; it++) {
    __syncthreads();
    if (it + 1 < nk) {
      int kt = (it + 1) << 6, nb = (it + 1) & 1;
      stage(Ag, lda, At[nb], kt);
      stage(Wg, ldw, Bt[nb], kt);
    }
    comp(At[it & 1], Bt[it & 1]);
  }
  epi(bn);
}

// ---------- causal flash attention: 128-q blocks, 32 q/wave, no-max softmax ----
// grid 768 (1-D, global LPT order), 256 thr. KVBLK=64 (R3-proven; 32 regressed
// twice: per-tile latency constant, critical path doubled, conflicts up).
__global__ __launch_bounds__(256, 2) void mla_attn(const short* __restrict__ Q,
                                                   const short* __restrict__ K,
                                                   const short* __restrict__ Vt,
                                                   short* __restrict__ O) {
  const int ld = 1536, SEQ = 2048;
  int tid = threadIdx.x, w = tid >> 6, lane = tid & 63;
  int quad = lane >> 4, l16 = lane & 15;
  int o = (int)blockIdx.x;
  int rank = o / 48;
  int g = o - rank * 48;
  int qt = (15 - rank) * 128;
  int hh = g % 12, b = g / 12;
  int qw = qt + w * 32;

  __shared__ short Kt[2][64 * 128];
  __shared__ short Vl[2][128 * 64];
  __shared__ short Pm[4][32 * 64];
  char* pwB = (char*)Pm[w];

  int kgo[4], vgo[4];
#pragma unroll
  for (int j = 0; j < 4; j++) {
    int rk = (w * 4 + j) * 4 + (lane >> 4);
    kgo[j] = rk * ld + (((lane & 15) ^ (rk & 7)) << 3);
    int rv = (w * 4 + j) * 8 + (lane >> 3);
    vgo[j] = rv * SEQ + (((lane & 7) ^ (rv & 7)) << 3);
  }
  const short* Kg = K + (size_t)b * SEQ * ld + hh * 128;
  const short* Vg = Vt + (size_t)(b * 12 + hh) * 128 * SEQ;

  short8 qf[2][4];
  {
    const short* Qg = Q + (size_t)(b * SEQ + qw + l16) * ld + hh * 128 + quad * 8;
#pragma unroll
    for (int nf = 0; nf < 2; nf++)
#pragma unroll
      for (int ks = 0; ks < 4; ks++)
        qf[nf][ks] = *(const short8*)(Qg + (size_t)nf * 16 * ld + ks * 32);
  }

  // ---- loop-invariant LDS byte offsets ----
  int koff[4][4], voff[2][8], pfo[2][2], pwo[2][4];
#pragma unroll
  for (int ks = 0; ks < 4; ks++)
#pragma unroll
    for (int mf = 0; mf < 4; mf++) {
      int row = mf * 16 + l16;
      koff[ks][mf] = row * 256 + ((((ks << 2) + quad) ^ (row & 7)) << 4);
    }
#pragma unroll
  for (int t = 0; t < 2; t++) {
#pragma unroll
    for (int df = 0; df < 8; df++) {
      int vr = df * 16 + l16;
      voff[t][df] = vr * 128 + ((((t << 2) + quad) ^ (vr & 7)) << 4);
    }
#pragma unroll
    for (int mq = 0; mq < 2; mq++)
      pfo[t][mq] = (mq * 16 + l16) * 128 + ((((t << 2) + quad) ^ (l16 & 7)) << 4);
#pragma unroll
    for (int mf = 0; mf < 4; mf++) {
      int p = (mf * 2 + (quad >> 1)) ^ (l16 & 7);
      pwo[t][mf] = (t * 16 + l16) * 128 + (p << 4) + ((quad & 1) << 3);
    }
  }

  float4v z = {0.f, 0.f, 0.f, 0.f};
  float4v oacc[2][8];
#pragma unroll
  for (int mq = 0; mq < 2; mq++)
#pragma unroll
    for (int df = 0; df < 8; df++) oacc[mq][df] = z;
  float l_i[2] = {0.f, 0.f};

#pragma unroll
  for (int j = 0; j < 4; j++) glds16(Kg + kgo[j], &Kt[0][(w * 4 + j) * 512]);
#pragma unroll
  for (int j = 0; j < 4; j++) glds16(Vg + vgo[j], &Vl[0][(w * 4 + j) * 512]);

  int ntiles = (qt >> 6) + 2;  // always even

#define ATTN_TILE(IT, NB, NB1)                                                 \
  do {                                                                         \
    int kt = (IT) << 6;                                                        \
    __syncthreads();                                                           \
    if ((IT) + 1 < ntiles) {                                                   \
      const short* kn = Kg + (size_t)(kt + 64) * ld;                           \
      const short* vn = Vg + (kt + 64);                                        \
      _Pragma("unroll") for (int j = 0; j < 4; j++)                            \
          glds16(kn + kgo[j], &Kt[NB1][(w * 4 + j) * 512]);                    \
      _Pragma("unroll") for (int j = 0; j < 4; j++)                            \
          glds16(vn + vgo[j], &Vl[NB1][(w * 4 + j) * 512]);                    \
    }                                                                          \
    if (kt <= qw + 31) {                                                       \
      const char* Kb = (const char*)Kt[NB];                                    \
      const char* Vb = (const char*)Vl[NB];                                    \
      float4v sf[4][2];                                                        \
      __builtin_amdgcn_s_setprio(1);                                           \
      _Pragma("unroll") for (int mf = 0; mf < 4; mf++) {                       \
        short8 a = *(const short8*)(Kb + koff[0][mf]);                         \
        sf[mf][0] = MFMA16(a, qf[0][0], z);                                    \
        sf[mf][1] = MFMA16(a, qf[1][0], z);                                    \
      }                                                                        \
      _Pragma("unroll") for (int ks = 1; ks < 4; ks++) {                       \
        _Pragma("unroll") for (int mf = 0; mf < 4; mf++) {                     \
          short8 a = *(const short8*)(Kb + koff[ks][mf]);                      \
          sf[mf][0] = MFMA16(a, qf[0][ks], sf[mf][0]);                         \
          sf[mf][1] = MFMA16(a, qf[1][ks], sf[mf][1]);                         \
        }                                                                      \
      }                                                                        \
      __builtin_amdgcn_s_setprio(0);                                           \
      if (kt + 63 > qw) {                                                      \
        _Pragma("unroll") for (int mf = 0; mf < 4; mf++) {                     \
          int key = kt + mf * 16 + quad * 4;                                   \
          _Pragma("unroll") for (int nf = 0; nf < 2; nf++) {                   \
            int q = qw + nf * 16 + l16;                                        \
            _Pragma("unroll") for (int r = 0; r < 4; r++)                      \
                if (key + r > q) sf[mf][nf][r] = -3e38f;                       \
          }                                                                    \
        }                                                                      \
      }                                                                        \
      _Pragma("unroll") for (int nf = 0; nf < 2; nf++) {                       \
        float ps = 0.f;                                                        \
        _Pragma("unroll") for (int mf = 0; mf < 4; mf++)                       \
            _Pragma("unroll") for (int r = 0; r < 4; r++) {                    \
          float e = exp2f(sf[mf][nf][r]);                                      \
          sf[mf][nf][r] = e;                                                   \
          ps += e;                                                             \
        }                                                                      \
        l_i[nf] += ps;                                                         \
        _Pragma("unroll") for (int mf = 0; mf < 4; mf++) {                     \
          int2v pk;                                                            \
          pk[0] = cvtpk(sf[mf][nf][0], sf[mf][nf][1]);                         \
          pk[1] = cvtpk(sf[mf][nf][2], sf[mf][nf][3]);                         \
          *(int2v*)(pwB + pwo[nf][mf]) = pk;                                   \
        }                                                                      \
      }                                                                        \
      __builtin_amdgcn_s_setprio(1);                                           \
      _Pragma("unroll") for (int t = 0; t < 2; t++) {                          \
        short8 pf0 = *(const short8*)(pwB + pfo[t][0]);                        \
        short8 pf1 = *(const short8*)(pwB + pfo[t][1]);                        \
        _Pragma("unroll") for (int df = 0; df < 8; df++) {                     \
          short8 vf = *(const short8*)(Vb + voff[t][df]);                      \
          oacc[0][df] = MFMA16(pf0, vf, oacc[0][df]);                          \
          oacc[1][df] = MFMA16(pf1, vf, oacc[1][df]);                          \
        }                                                                      \
      }                                                                        \
      __builtin_amdgcn_s_setprio(0);                                           \
    }                                                                          \
  } while (0)

  for (int it = 0; it < ntiles; it += 2) {
    ATTN_TILE(it, 0, 1);
    ATTN_TILE(it + 1, 1, 0);
  }
#undef ATTN_TILE

  // ---- epilogue: reduce l across quads, scale, store ----
  short* Og = O + (size_t)(b * SEQ + qw) * ld + hh * 128;
#pragma unroll
  for (int mq = 0; mq < 2; mq++) {
    float l = l_i[mq];
    l += __shfl_xor(l, 16, 64);
    l += __shfl_xor(l, 32, 64);
    float linv = 1.0f / l;
    float lb[4];
#pragma unroll
    for (int r = 0; r < 4; r++) lb[r] = __shfl(linv, (quad << 2) + r, 64);
#pragma unroll
    for (int df = 0; df < 8; df++)
#pragma unroll
      for (int r = 0; r < 4; r++)
        Og[(size_t)(mq * 16 + (quad << 2) + r) * ld + df * 16 + l16] =
            f2bf(oacc[mq][df][r] * lb[r]);
  }
}

// ---------- launcher ----------
extern "C" void kernel_launch(void* const* d_in, const int* in_sizes, int n_in,
                              void* d_out, int out_size, void* d_ws, size_t ws_size,
                              hipStream_t stream) {
  const int S = 2048, DM = 768, DL = 128, HD = 1536;
  const int M = 4 * S;  // 8192
  const int BIG = 1 << 28;

  const float* x = (const float*)d_in[0];
  const int* pos = (const int*)d_in[1];
  const float* W_dkv = (const float*)d_in[2];
  const float* b_dkv = (const float*)d_in[3];
  const float* W_dq = (const float*)d_in[4];
  const float* b_dq = (const float*)d_in[5];
  const float* W_uk_nope = (const float*)d_in[6];
  const float* b_uk_nope = (const float*)d_in[7];
  const float* W_uv = (const float*)d_in[8];
  const float* b_uv = (const float*)d_in[9];
  const float* W_uq_nope = (const float*)d_in[10];
  const float* b_uq_nope = (const float*)d_in[11];
  const float* W_uq_rope = (const float*)d_in[12];
  const float* b_uq_rope = (const float*)d_in[13];
  const float* W_uk_rope = (const float*)d_in[14];
  const float* b_uk_rope = (const float*)d_in[15];
  const float* W_o = (const float*)d_in[16];
  const float* b_o = (const float*)d_in[17];

  char* p = (char*)d_ws;
  size_t off = 0;
  auto take = [&](size_t nelem) -> short* {
    short* r = (short*)(p + off);
    off += (nelem * 2 + 255) & ~(size_t)255;
    return r;
  };
  short* xb = take((size_t)M * DM);
  short* Wdq = take(DL * DM);
  short* Wdkv = take(DL * DM);
  short* Wuqnope = take(768 * DL);
  short* Wuqrope = take(768 * DL);
  short* Wuknope = take(768 * DL);
  short* Wuv = take(1536 * DL);
  short* Wukrope = take(768 * DM);
  short* Wo = take(768 * 1536);
  short* Cm = take((size_t)M * 256);  // [C_q | C_kv]
  short* Qm = take((size_t)M * HD);
  short* Km = take((size_t)M * HD);
  short* Vtm = take((size_t)M * HD);  // V^T: [b][h*128+d][s]
  short* Om = take((size_t)M * HD);
  if (off > ws_size) return;

  CastArgs ca;
  const float* srcs[9] = {x, W_dq, W_dkv, W_uq_nope, W_uq_rope, W_uk_nope, W_uv, W_uk_rope, W_o};
  short* dsts[9] = {xb, Wdq, Wdkv, Wuqnope, Wuqrope, Wuknope, Wuv, Wukrope, Wo};
  int ns[9] = {M * DM, DL * DM, DL * DM, 768 * DL, 768 * DL, 768 * DL, 1536 * DL, 768 * DM, 768 * 1536};
  ca.start[0] = 0;
  for (int i = 0; i < 9; i++) {
    ca.seg[i].src = srcs[i];
    ca.seg[i].dst = dsts[i];
    ca.seg[i].n4 = ns[i] / 4;
    ca.start[i + 1] = ca.start[i] + (ca.seg[i].n4 + 255) / 256;
  }
  castk<<<dim3(ca.start[9]), dim3(256), 0, stream>>>(ca);

  // ---- launch 1: C (N=256,K=768) || rope(k_rope) (N=768,K=768) ----
  GArgs g1;
  g1.s[0].A = xb;   g1.s[0].W = Wdq;      g1.s[0].bias0 = b_dq;      g1.s[0].bias1 = b_dkv;
  g1.s[0].outp = Cm; g1.s[0].lda = DM; g1.s[0].ldw = DM; g1.s[0].bsplit = 128;
  g1.s[0].ropestart = 0; g1.s[0].ldo = 256; g1.s[0].ocol = 0; g1.s[0].K = DM;
  g1.s[0].flags = 0; g1.s[0].ntile = 1;
  g1.s[1].A = xb;   g1.s[1].W = Wukrope;  g1.s[1].bias0 = b_uk_rope; g1.s[1].bias1 = b_uk_rope;
  g1.s[1].outp = Km; g1.s[1].lda = DM; g1.s[1].ldw = DM; g1.s[1].bsplit = BIG;
  g1.s[1].ropestart = 0; g1.s[1].ldo = HD; g1.s[1].ocol = 768; g1.s[1].K = DM;
  g1.s[1].flags = 1; g1.s[1].ntile = 1;
  g1.s[2] = g1.s[1];
  g1.start[0] = 0; g1.start[1] = 2; g1.start[2] = 8; g1.start[3] = 8;
  gemm_rt<1><<<dim3(M / 128, 8), dim3(256), 0, stream>>>(g1, pos);

  // ---- launch 2: Q (quad) || k_nope (pair) || V^T (pair), all K=128 ----
  GArgs g2;
  g2.s[0].A = Cm;   g2.s[0].W = Wuqnope;  g2.s[0].bias0 = b_uq_nope; g2.s[0].bias1 = b_uq_rope;
  g2.s[0].outp = Qm; g2.s[0].lda = 256; g2.s[0].ldw = DL; g2.s[0].bsplit = 768;
  g2.s[0].ropestart = 768; g2.s[0].ldo = HD; g2.s[0].ocol = 0; g2.s[0].K = DL;
  g2.s[0].flags = 1 | 2; g2.s[0].ntile = 4;
  g2.s[1].A = Cm + 128; g2.s[1].W = Wuknope; g2.s[1].bias0 = b_uk_nope; g2.s[1].bias1 = b_uk_nope;
  g2.s[1].outp = Km; g2.s[1].lda = 256; g2.s[1].ldw = DL; g2.s[1].bsplit = BIG;
  g2.s[1].ropestart = 0; g2.s[1].ldo = HD; g2.s[1].ocol = 0; g2.s[1].K = DL;
  g2.s[1].flags = 0; g2.s[1].ntile = 2;
  g2.s[2].A = Cm + 128; g2.s[2].W = Wuv;   g2.s[2].bias0 = b_uv;      g2.s[2].bias1 = b_uv;
  g2.s[2].outp = Vtm; g2.s[2].lda = 256; g2.s[2].ldw = DL; g2.s[2].bsplit = BIG;
  g2.s[2].ropestart = 0; g2.s[2].ldo = 0; g2.s[2].ocol = 0; g2.s[2].K = DL;
  g2.s[2].flags = 4; g2.s[2].ntile = 2;
  g2.start[0] = 0; g2.start[1] = 3; g2.start[2] = 6; g2.start[3] = 12;
  gemm_rt<2><<<dim3(M / 128, 12), dim3(256), 0, stream>>>(g2, pos);

  // ---- attention: 768 blocks, global longest-first (LPT) order ----
  mla_attn<<<dim3(768), dim3(256), 0, stream>>>(Qm, Km, Vtm, Om);

  // ---- launch 3: out = O @ W_o^T + b_o (N=768, K=1536, fp32 out) ----
  GArgs g3;
  g3.s[0].A = Om;   g3.s[0].W = Wo;       g3.s[0].bias0 = b_o;       g3.s[0].bias1 = b_o;
  g3.s[0].outp = d_out; g3.s[0].lda = HD; g3.s[0].ldw = HD; g3.s[0].bsplit = BIG;
  g3.s[0].ropestart = 0; g3.s[0].ldo = 768; g3.s[0].ocol = 0; g3.s[0].K = HD;
  g3.s[0].flags = 8; g3.s[0].ntile = 1;
  g3.s[1] = g3.s[0];
  g3.s[2] = g3.s[0];
  g3.start[0] = 0; g3.start[1] = 6; g3.start[2] = 6; g3.start[3] = 6;
  gemm_rt<3><<<dim3(M / 128, 6), dim3(256), 0, stream>>>(g3, pos);
}

// Round 7
// 306.820 us; speedup vs baseline: 1.4284x; 1.3601x over previous
//
#include <hip/hip_runtime.h>

// ---------- types ----------
typedef __attribute__((ext_vector_type(8))) short short8;   // 8 x bf16
typedef __attribute__((ext_vector_type(4))) short short4v;  // 4 x bf16
typedef __attribute__((ext_vector_type(2))) int int2v;
typedef __attribute__((ext_vector_type(4))) float float4v;

#define MFMA16(a, b, c) __builtin_amdgcn_mfma_f32_16x16x32_bf16((a), (b), (c), 0, 0, 0)

__device__ __forceinline__ short f2bf(float f) {  // RNE fp32 -> bf16
  unsigned u = __float_as_uint(f);
  u += 0x7fffu + ((u >> 16) & 1u);
  return (short)(u >> 16);
}

// packed fp32x2 -> bf16x2 (RNE) in one VALU op
__device__ __forceinline__ int cvtpk(float a, float b) {
  int r;
  asm("v_cvt_pk_bf16_f32 %0, %1, %2" : "=v"(r) : "v"(a), "v"(b));
  return r;
}

// async global->LDS, 16B per lane; LDS dest = wave-uniform base + lane*16
__device__ __forceinline__ void glds16(const short* g, short* l) {
  __builtin_amdgcn_global_load_lds(
      (const __attribute__((address_space(1))) void*)g,
      (__attribute__((address_space(3))) void*)l, 16, 0, 0);
}

// ---------- fused fp32 -> bf16 cast (all 9 tensors, one launch) ----------
struct CastSeg { const float* src; short* dst; int n4; };
struct CastArgs { CastSeg seg[9]; int start[10]; };

__global__ __launch_bounds__(256) void castk(CastArgs a) {
  int blk = blockIdx.x;
  int si = 0;
#pragma unroll
  for (int i = 1; i < 9; i++) si += (blk >= a.start[i]);
  int i = (blk - a.start[si]) * 256 + threadIdx.x;
  if (i >= a.seg[si].n4) return;
  float4v f = ((const float4v*)a.seg[si].src)[i];
  short4v o;
  o[0] = f2bf(f[0]); o[1] = f2bf(f[1]); o[2] = f2bf(f[2]); o[3] = f2bf(f[3]);
  ((short4v*)a.seg[si].dst)[i] = o;
}

// ---------- segmented runtime-flag MFMA GEMM (R3-verified 304us config) ----------
// out[m, ocol+n] = A(M,K) @ W(N,K)^T + bias. Block 128x128, 4 waves 2x2.
// BK=64, glds16 staging, XOR chunk swizzle.
// Grid: blockIdx.x = m-tile (fastest) -> flat%8 == m-tile%8 -> each XCD owns
// a set of m-rows; row-operand (x/Cm/Om) is HBM-fetched once, L2-hit after.
// blockIdx.y = bn-unit, segmented.
// flags: 1=ROPE, 2=SCALE, 4=V^T out (LDS-transposed coalesced store),
//        8=fp32 out, 16=bn-pair (two 128-col tiles per block, K=128 only)
// Three identically-bodied wrappers (gemm_c/q/o) exist ONLY so rocprof shows
// distinct Kernel_Name per launch (template args are stripped in the CSV).
struct GSeg {
  const short* A;
  const short* W;
  const float* bias0;
  const float* bias1;
  void* outp;
  int lda, ldw, bsplit, ropestart, ldo, ocol, K, flags;
};
struct GArgs { GSeg s[3]; int start[4]; };

__device__ __forceinline__ void gemm_body(const GArgs& ga, const int* __restrict__ pos) {
  int by = blockIdx.y;
  int si = (by >= ga.start[1]) + (by >= ga.start[2]);
  const GSeg sg = ga.s[si];
  int tid = threadIdx.x, w = tid >> 6, lane = tid & 63;
  int quad = lane >> 4, l16 = lane & 15;
  bool ropeF = sg.flags & 1, scaleF = sg.flags & 2;
  bool vtF = sg.flags & 4, f32F = sg.flags & 8, pairF = sg.flags & 16;
  int bm = blockIdx.x * 128;
  int bn = (by - ga.start[si]) * (pairF ? 256 : 128);
  int wm = (w & 1) * 64, wn = (w >> 1) * 64;
  int lda = sg.lda, ldw = sg.ldw;

  __shared__ short At[2][128 * 64];
  __shared__ short Bt[2][128 * 64];

  int srow[4], soff[4];
#pragma unroll
  for (int j = 0; j < 4; j++) {
    int r = w * 32 + j * 8 + (lane >> 3);
    srow[j] = r;
    soff[j] = ((lane & 7) ^ (r & 7)) << 3;
  }
  const short* Ag = sg.A + (size_t)bm * lda;
  const short* Wg = sg.W + (size_t)bn * ldw;

  float4v acc[4][4];
  float4v z = {0.f, 0.f, 0.f, 0.f};
#pragma unroll
  for (int mi = 0; mi < 4; mi++)
#pragma unroll
    for (int ni = 0; ni < 4; ni++) acc[mi][ni] = z;

  auto comp = [&](const short* Ab, const short* Bb) {
#pragma unroll
    for (int ks = 0; ks < 2; ks++) {
      short8 af[4], bf[4];
#pragma unroll
      for (int mi = 0; mi < 4; mi++) {
        int row = wm + mi * 16 + l16;
        af[mi] = *(const short8*)&Ab[(row << 6) + ((((ks << 2) + quad) ^ (row & 7)) << 3)];
      }
#pragma unroll
      for (int ni = 0; ni < 4; ni++) {
        int row = wn + ni * 16 + l16;
        bf[ni] = *(const short8*)&Bb[(row << 6) + ((((ks << 2) + quad) ^ (row & 7)) << 3)];
      }
#pragma unroll
      for (int mi = 0; mi < 4; mi++)
#pragma unroll
        for (int ni = 0; ni < 4; ni++)
          acc[mi][ni] = MFMA16(af[mi], bf[ni], acc[mi][ni]);
    }
  };

  // ---- epilogue (runtime flags; block-uniform branches) ----
  auto epi = [&](int bnX) {
    if (vtF) {
      // transpose 128x128 tile through LDS (At as scratch), coalesced store
      __syncthreads();  // all waves done reading At/Bt
      short* T = &At[0][0];  // 32KB: T[col*128 + rotated_row]
#pragma unroll
      for (int ni = 0; ni < 4; ni++) {
        int col = wn + ni * 16 + l16;
        float bv = sg.bias0[bnX + col];
#pragma unroll
        for (int mi = 0; mi < 4; mi++) {
          int row0 = wm + mi * 16 + quad * 4;
          int rr = (row0 + ((col & 15) << 3)) & 127;
          short4v ov;
#pragma unroll
          for (int r = 0; r < 4; r++) ov[r] = f2bf(acc[mi][ni][r] + bv);
          *(short4v*)&T[col * 128 + rr] = ov;
        }
      }
      __syncthreads();
      int bidx = bm >> 11, s0 = bm & 2047;
      int sc = tid & 15;
#pragma unroll
      for (int cc = 0; cc < 8; cc++) {
        int c = cc * 16 + (tid >> 4);
        int rr = ((sc + (c & 15)) << 3) & 127;
        short8 v = *(const short8*)&T[c * 128 + rr];
        *(short8*)((short*)sg.outp + ((size_t)(bidx * 1536 + bnX + c)) * 2048 +
                   s0 + (sc << 3)) = v;
      }
      return;
    }
#pragma unroll
    for (int ni = 0; ni < 4; ni++) {
      int col = bnX + wn + ni * 16 + l16;
      float bv = (col < sg.bsplit) ? sg.bias0[col] : sg.bias1[col - sg.bsplit];
      float fr = 0.f;
      bool dorope = ropeF && (col >= sg.ropestart);
      if (dorope) {
        int ri = (col - sg.ropestart) & ~1;
        fr = exp2f((float)ri * (-13.287712379549449f / 768.0f));
      }
#pragma unroll
      for (int mi = 0; mi < 4; mi++) {
        int row0 = bm + wm + mi * 16 + quad * 4;
#pragma unroll
        for (int r = 0; r < 4; r++) {
          int row = row0 + r;
          float v = acc[mi][ni][r] + bv;
          if (ropeF) {
            float pv = __shfl_xor(v, 1, 64);
            if (dorope) {
              float ang = (float)pos[row & 2047] * fr;
              float sn, cs;
              __sincosf(ang, &sn, &cs);
              v = (col & 1) ? (pv * sn + v * cs) : (v * cs - pv * sn);
            }
          }
          if (scaleF) v *= 0.12751743f;  // (1/sqrt(128)) * log2(e)
          if (f32F)
            ((float*)sg.outp)[(size_t)row * sg.ldo + sg.ocol + col] = v;
          else
            ((short*)sg.outp)[(size_t)row * sg.ldo + sg.ocol + col] = f2bf(v);
        }
      }
    }
  };

  int nk = sg.K >> 6;
  if (nk == 2) {
    // thin-K fast path: stage K=128 entirely, one barrier
    auto stageB = [&](const short* Wg2) {
#pragma unroll
      for (int j = 0; j < 4; j++) {
        glds16(Wg2 + (size_t)srow[j] * ldw + soff[j], &Bt[0][(w * 32 + j * 8) * 64]);
        glds16(Wg2 + (size_t)srow[j] * ldw + 64 + soff[j], &Bt[1][(w * 32 + j * 8) * 64]);
      }
    };
#pragma unroll
    for (int j = 0; j < 4; j++) {
      glds16(Ag + (size_t)srow[j] * lda + soff[j], &At[0][(w * 32 + j * 8) * 64]);
      glds16(Ag + (size_t)srow[j] * lda + 64 + soff[j], &At[1][(w * 32 + j * 8) * 64]);
    }
    stageB(Wg);
    __syncthreads();
    comp(At[0], Bt[0]);
    comp(At[1], Bt[1]);
    if (pairF) {
      __syncthreads();            // waves done reading Bt
      stageB(Wg + (size_t)128 * ldw);  // DMA next B tile under epilogue
      epi(bn);
#pragma unroll
      for (int mi = 0; mi < 4; mi++)
#pragma unroll
        for (int ni = 0; ni < 4; ni++) acc[mi][ni] = z;
      __syncthreads();            // drains glds16
      comp(At[0], Bt[0]);
      comp(At[1], Bt[1]);
      epi(bn + 128);
    } else {
      epi(bn);
    }
  } else {
#pragma unroll
    for (int j = 0; j < 4; j++)
      glds16(Ag + (size_t)srow[j] * lda + soff[j], &At[0][(w * 32 + j * 8) * 64]);
#pragma unroll
    for (int j = 0; j < 4; j++)
      glds16(Wg + (size_t)srow[j] * ldw + soff[j], &Bt[0][(w * 32 + j * 8) * 64]);
    for (int it = 0; it < nk; it++) {
      __syncthreads();
      if (it + 1 < nk) {
        int kt = (it + 1) << 6, nb = (it + 1) & 1;
#pragma unroll
        for (int j = 0; j < 4; j++)
          glds16(Ag + (size_t)srow[j] * lda + kt + soff[j],
                 &At[nb][(w * 32 + j * 8) * 64]);
#pragma unroll
        for (int j = 0; j < 4; j++)
          glds16(Wg + (size_t)srow[j] * ldw + kt + soff[j],
                 &Bt[nb][(w * 32 + j * 8) * 64]);
      }
      comp(At[it & 1], Bt[it & 1]);
    }
    epi(bn);
  }
}

__global__ __launch_bounds__(256, 2) void gemm_c(GArgs ga, const int* __restrict__ pos) {
  gemm_body(ga, pos);
}
__global__ __launch_bounds__(256, 2) void gemm_q(GArgs ga, const int* __restrict__ pos) {
  gemm_body(ga, pos);
}
__global__ __launch_bounds__(256, 2) void gemm_o(GArgs ga, const int* __restrict__ pos) {
  gemm_body(ga, pos);
}

// ---------- causal flash attention: 128-q blocks, 32 q/wave, no-max softmax ----
// grid 768 (1-D, global LPT order), 256 thr. KVBLK=64 (R3-verified 85.4us).
__global__ __launch_bounds__(256, 2) void mla_attn(const short* __restrict__ Q,
                                                   const short* __restrict__ K,
                                                   const short* __restrict__ Vt,
                                                   short* __restrict__ O) {
  const int ld = 1536, SEQ = 2048;
  int tid = threadIdx.x, w = tid >> 6, lane = tid & 63;
  int quad = lane >> 4, l16 = lane & 15;
  int o = (int)blockIdx.x;
  int rank = o / 48;
  int g = o - rank * 48;
  int qt = (15 - rank) * 128;
  int hh = g % 12, b = g / 12;
  int qw = qt + w * 32;

  __shared__ short Kt[2][64 * 128];
  __shared__ short Vl[2][128 * 64];
  __shared__ short Pm[4][32 * 64];
  char* pwB = (char*)Pm[w];

  int kgo[4], vgo[4];
#pragma unroll
  for (int j = 0; j < 4; j++) {
    int rk = (w * 4 + j) * 4 + (lane >> 4);
    kgo[j] = rk * ld + (((lane & 15) ^ (rk & 7)) << 3);
    int rv = (w * 4 + j) * 8 + (lane >> 3);
    vgo[j] = rv * SEQ + (((lane & 7) ^ (rv & 7)) << 3);
  }
  const short* Kg = K + (size_t)b * SEQ * ld + hh * 128;
  const short* Vg = Vt + (size_t)(b * 12 + hh) * 128 * SEQ;

  short8 qf[2][4];
  {
    const short* Qg = Q + (size_t)(b * SEQ + qw + l16) * ld + hh * 128 + quad * 8;
#pragma unroll
    for (int nf = 0; nf < 2; nf++)
#pragma unroll
      for (int ks = 0; ks < 4; ks++)
        qf[nf][ks] = *(const short8*)(Qg + (size_t)nf * 16 * ld + ks * 32);
  }

  // ---- loop-invariant LDS byte offsets ----
  int koff[4][4], voff[2][8], pfo[2][2], pwo[2][4];
#pragma unroll
  for (int ks = 0; ks < 4; ks++)
#pragma unroll
    for (int mf = 0; mf < 4; mf++) {
      int row = mf * 16 + l16;
      koff[ks][mf] = row * 256 + ((((ks << 2) + quad) ^ (row & 7)) << 4);
    }
#pragma unroll
  for (int t = 0; t < 2; t++) {
#pragma unroll
    for (int df = 0; df < 8; df++) {
      int vr = df * 16 + l16;
      voff[t][df] = vr * 128 + ((((t << 2) + quad) ^ (vr & 7)) << 4);
    }
#pragma unroll
    for (int mq = 0; mq < 2; mq++)
      pfo[t][mq] = (mq * 16 + l16) * 128 + ((((t << 2) + quad) ^ (l16 & 7)) << 4);
#pragma unroll
    for (int mf = 0; mf < 4; mf++) {
      int p = (mf * 2 + (quad >> 1)) ^ (l16 & 7);
      pwo[t][mf] = (t * 16 + l16) * 128 + (p << 4) + ((quad & 1) << 3);
    }
  }

  float4v z = {0.f, 0.f, 0.f, 0.f};
  float4v oacc[2][8];
#pragma unroll
  for (int mq = 0; mq < 2; mq++)
#pragma unroll
    for (int df = 0; df < 8; df++) oacc[mq][df] = z;
  float l_i[2] = {0.f, 0.f};

#pragma unroll
  for (int j = 0; j < 4; j++) glds16(Kg + kgo[j], &Kt[0][(w * 4 + j) * 512]);
#pragma unroll
  for (int j = 0; j < 4; j++) glds16(Vg + vgo[j], &Vl[0][(w * 4 + j) * 512]);

  int ntiles = (qt >> 6) + 2;  // always even

#define ATTN_TILE(IT, NB, NB1)                                                 \
  do {                                                                         \
    int kt = (IT) << 6;                                                        \
    __syncthreads();                                                           \
    if ((IT) + 1 < ntiles) {                                                   \
      const short* kn = Kg + (size_t)(kt + 64) * ld;                           \
      const short* vn = Vg + (kt + 64);                                        \
      _Pragma("unroll") for (int j = 0; j < 4; j++)                            \
          glds16(kn + kgo[j], &Kt[NB1][(w * 4 + j) * 512]);                    \
      _Pragma("unroll") for (int j = 0; j < 4; j++)                            \
          glds16(vn + vgo[j], &Vl[NB1][(w * 4 + j) * 512]);                    \
    }                                                                          \
    if (kt <= qw + 31) {                                                       \
      const char* Kb = (const char*)Kt[NB];                                    \
      const char* Vb = (const char*)Vl[NB];                                    \
      float4v sf[4][2];                                                        \
      __builtin_amdgcn_s_setprio(1);                                           \
      _Pragma("unroll") for (int mf = 0; mf < 4; mf++) {                       \
        short8 a = *(const short8*)(Kb + koff[0][mf]);                         \
        sf[mf][0] = MFMA16(a, qf[0][0], z);                                    \
        sf[mf][1] = MFMA16(a, qf[1][0], z);                                    \
      }                                                                        \
      _Pragma("unroll") for (int ks = 1; ks < 4; ks++) {                       \
        _Pragma("unroll") for (int mf = 0; mf < 4; mf++) {                     \
          short8 a = *(const short8*)(Kb + koff[ks][mf]);                      \
          sf[mf][0] = MFMA16(a, qf[0][ks], sf[mf][0]);                         \
          sf[mf][1] = MFMA16(a, qf[1][ks], sf[mf][1]);                         \
        }                                                                      \
      }                                                                        \
      __builtin_amdgcn_s_setprio(0);                                           \
      if (kt + 63 > qw) {                                                      \
        _Pragma("unroll") for (int mf = 0; mf < 4; mf++) {                     \
          int key = kt + mf * 16 + quad * 4;                                   \
          _Pragma("unroll") for (int nf = 0; nf < 2; nf++) {                   \
            int q = qw + nf * 16 + l16;                                        \
            _Pragma("unroll") for (int r = 0; r < 4; r++)                      \
                if (key + r > q) sf[mf][nf][r] = -3e38f;                       \
          }                                                                    \
        }                                                                      \
      }                                                                        \
      _Pragma("unroll") for (int nf = 0; nf < 2; nf++) {                       \
        float ps = 0.f;                                                        \
        _Pragma("unroll") for (int mf = 0; mf < 4; mf++)                       \
            _Pragma("unroll") for (int r = 0; r < 4; r++) {                    \
          float e = exp2f(sf[mf][nf][r]);                                      \
          sf[mf][nf][r] = e;                                                   \
          ps += e;                                                             \
        }                                                                      \
        l_i[nf] += ps;                                                         \
        _Pragma("unroll") for (int mf = 0; mf < 4; mf++) {                     \
          int2v pk;                                                            \
          pk[0] = cvtpk(sf[mf][nf][0], sf[mf][nf][1]);                         \
          pk[1] = cvtpk(sf[mf][nf][2], sf[mf][nf][3]);                         \
          *(int2v*)(pwB + pwo[nf][mf]) = pk;                                   \
        }                                                                      \
      }                                                                        \
      __builtin_amdgcn_s_setprio(1);                                           \
      _Pragma("unroll") for (int t = 0; t < 2; t++) {                          \
        short8 pf0 = *(const short8*)(pwB + pfo[t][0]);                        \
        short8 pf1 = *(const short8*)(pwB + pfo[t][1]);                        \
        _Pragma("unroll") for (int df = 0; df < 8; df++) {                     \
          short8 vf = *(const short8*)(Vb + voff[t][df]);                      \
          oacc[0][df] = MFMA16(pf0, vf, oacc[0][df]);                          \
          oacc[1][df] = MFMA16(pf1, vf, oacc[1][df]);                          \
        }                                                                      \
      }                                                                        \
      __builtin_amdgcn_s_setprio(0);                                           \
    }                                                                          \
  } while (0)

  for (int it = 0; it < ntiles; it += 2) {
    ATTN_TILE(it, 0, 1);
    ATTN_TILE(it + 1, 1, 0);
  }
#undef ATTN_TILE

  // ---- epilogue: reduce l across quads, scale, store ----
  short* Og = O + (size_t)(b * SEQ + qw) * ld + hh * 128;
#pragma unroll
  for (int mq = 0; mq < 2; mq++) {
    float l = l_i[mq];
    l += __shfl_xor(l, 16, 64);
    l += __shfl_xor(l, 32, 64);
    float linv = 1.0f / l;
    float lb[4];
#pragma unroll
    for (int r = 0; r < 4; r++) lb[r] = __shfl(linv, (quad << 2) + r, 64);
#pragma unroll
    for (int df = 0; df < 8; df++)
#pragma unroll
      for (int r = 0; r < 4; r++)
        Og[(size_t)(mq * 16 + (quad << 2) + r) * ld + df * 16 + l16] =
            f2bf(oacc[mq][df][r] * lb[r]);
  }
}

// ---------- launcher ----------
extern "C" void kernel_launch(void* const* d_in, const int* in_sizes, int n_in,
                              void* d_out, int out_size, void* d_ws, size_t ws_size,
                              hipStream_t stream) {
  const int S = 2048, DM = 768, DL = 128, HD = 1536;
  const int M = 4 * S;  // 8192
  const int BIG = 1 << 28;

  const float* x = (const float*)d_in[0];
  const int* pos = (const int*)d_in[1];
  const float* W_dkv = (const float*)d_in[2];
  const float* b_dkv = (const float*)d_in[3];
  const float* W_dq = (const float*)d_in[4];
  const float* b_dq = (const float*)d_in[5];
  const float* W_uk_nope = (const float*)d_in[6];
  const float* b_uk_nope = (const float*)d_in[7];
  const float* W_uv = (const float*)d_in[8];
  const float* b_uv = (const float*)d_in[9];
  const float* W_uq_nope = (const float*)d_in[10];
  const float* b_uq_nope = (const float*)d_in[11];
  const float* W_uq_rope = (const float*)d_in[12];
  const float* b_uq_rope = (const float*)d_in[13];
  const float* W_uk_rope = (const float*)d_in[14];
  const float* b_uk_rope = (const float*)d_in[15];
  const float* W_o = (const float*)d_in[16];
  const float* b_o = (const float*)d_in[17];

  char* p = (char*)d_ws;
  size_t off = 0;
  auto take = [&](size_t nelem) -> short* {
    short* r = (short*)(p + off);
    off += (nelem * 2 + 255) & ~(size_t)255;
    return r;
  };
  short* xb = take((size_t)M * DM);
  short* Wdq = take(DL * DM);
  short* Wdkv = take(DL * DM);
  short* Wuqnope = take(768 * DL);
  short* Wuqrope = take(768 * DL);
  short* Wuknope = take(768 * DL);
  short* Wuv = take(1536 * DL);
  short* Wukrope = take(768 * DM);
  short* Wo = take(768 * 1536);
  short* Cm = take((size_t)M * 256);  // [C_q | C_kv]
  short* Qm = take((size_t)M * HD);
  short* Km = take((size_t)M * HD);
  short* Vtm = take((size_t)M * HD);  // V^T: [b][h*128+d][s]
  short* Om = take((size_t)M * HD);
  if (off > ws_size) return;

  CastArgs ca;
  const float* srcs[9] = {x, W_dq, W_dkv, W_uq_nope, W_uq_rope, W_uk_nope, W_uv, W_uk_rope, W_o};
  short* dsts[9] = {xb, Wdq, Wdkv, Wuqnope, Wuqrope, Wuknope, Wuv, Wukrope, Wo};
  int ns[9] = {M * DM, DL * DM, DL * DM, 768 * DL, 768 * DL, 768 * DL, 1536 * DL, 768 * DM, 768 * 1536};
  ca.start[0] = 0;
  for (int i = 0; i < 9; i++) {
    ca.seg[i].src = srcs[i];
    ca.seg[i].dst = dsts[i];
    ca.seg[i].n4 = ns[i] / 4;
    ca.start[i + 1] = ca.start[i] + (ca.seg[i].n4 + 255) / 256;
  }
  castk<<<dim3(ca.start[9]), dim3(256), 0, stream>>>(ca);

  // ---- launch 1: C (N=256,K=768) || rope(k_rope) (N=768,K=768) ----
  GArgs g1;
  g1.s[0].A = xb;   g1.s[0].W = Wdq;      g1.s[0].bias0 = b_dq;      g1.s[0].bias1 = b_dkv;
  g1.s[0].outp = Cm; g1.s[0].lda = DM; g1.s[0].ldw = DM; g1.s[0].bsplit = 128;
  g1.s[0].ropestart = 0; g1.s[0].ldo = 256; g1.s[0].ocol = 0; g1.s[0].K = DM; g1.s[0].flags = 0;
  g1.s[1].A = xb;   g1.s[1].W = Wukrope;  g1.s[1].bias0 = b_uk_rope; g1.s[1].bias1 = b_uk_rope;
  g1.s[1].outp = Km; g1.s[1].lda = DM; g1.s[1].ldw = DM; g1.s[1].bsplit = BIG;
  g1.s[1].ropestart = 0; g1.s[1].ldo = HD; g1.s[1].ocol = 768; g1.s[1].K = DM; g1.s[1].flags = 1;
  g1.s[2] = g1.s[1];
  g1.start[0] = 0; g1.start[1] = 2; g1.start[2] = 8; g1.start[3] = 8;
  gemm_c<<<dim3(M / 128, 8), dim3(256), 0, stream>>>(g1, pos);

  // ---- launch 2: Q (N=1536,paired) || k_nope (N=768,paired) || V^T (N=1536) ----
  GArgs g2;
  g2.s[0].A = Cm;   g2.s[0].W = Wuqnope;  g2.s[0].bias0 = b_uq_nope; g2.s[0].bias1 = b_uq_rope;
  g2.s[0].outp = Qm; g2.s[0].lda = 256; g2.s[0].ldw = DL; g2.s[0].bsplit = 768;
  g2.s[0].ropestart = 768; g2.s[0].ldo = HD; g2.s[0].ocol = 0; g2.s[0].K = DL;
  g2.s[0].flags = 1 | 2 | 16;
  g2.s[1].A = Cm + 128; g2.s[1].W = Wuknope; g2.s[1].bias0 = b_uk_nope; g2.s[1].bias1 = b_uk_nope;
  g2.s[1].outp = Km; g2.s[1].lda = 256; g2.s[1].ldw = DL; g2.s[1].bsplit = BIG;
  g2.s[1].ropestart = 0; g2.s[1].ldo = HD; g2.s[1].ocol = 0; g2.s[1].K = DL;
  g2.s[1].flags = 16;
  g2.s[2].A = Cm + 128; g2.s[2].W = Wuv;   g2.s[2].bias0 = b_uv;      g2.s[2].bias1 = b_uv;
  g2.s[2].outp = Vtm; g2.s[2].lda = 256; g2.s[2].ldw = DL; g2.s[2].bsplit = BIG;
  g2.s[2].ropestart = 0; g2.s[2].ldo = 0; g2.s[2].ocol = 0; g2.s[2].K = DL;
  g2.s[2].flags = 4;
  g2.start[0] = 0; g2.start[1] = 6; g2.start[2] = 9; g2.start[3] = 21;
  gemm_q<<<dim3(M / 128, 21), dim3(256), 0, stream>>>(g2, pos);

  // ---- attention: 768 blocks, global longest-first (LPT) order ----
  mla_attn<<<dim3(768), dim3(256), 0, stream>>>(Qm, Km, Vtm, Om);

  // ---- launch 3: out = O @ W_o^T + b_o (N=768, K=1536, fp32 out) ----
  GArgs g3;
  g3.s[0].A = Om;   g3.s[0].W = Wo;       g3.s[0].bias0 = b_o;       g3.s[0].bias1 = b_o;
  g3.s[0].outp = d_out; g3.s[0].lda = HD; g3.s[0].ldw = HD; g3.s[0].bsplit = BIG;
  g3.s[0].ropestart = 0; g3.s[0].ldo = 768; g3.s[0].ocol = 0; g3.s[0].K = HD; g3.s[0].flags = 8;
  g3.s[1] = g3.s[0];
  g3.s[2] = g3.s[0];
  g3.start[0] = 0; g3.start[1] = 6; g3.start[2] = 6; g3.start[3] = 6;
  gemm_o<<<dim3(M / 128, 6), dim3(256), 0, stream>>>(g3, pos);
}

// Round 8
// 295.473 us; speedup vs baseline: 1.4833x; 1.0384x over previous
//
#include <hip/hip_runtime.h>

// ---------- types ----------
typedef __attribute__((ext_vector_type(8))) short short8;   // 8 x bf16
typedef __attribute__((ext_vector_type(4))) short short4v;  // 4 x bf16
typedef __attribute__((ext_vector_type(2))) int int2v;
typedef __attribute__((ext_vector_type(4))) float float4v;

#define MFMA16(a, b, c) __builtin_amdgcn_mfma_f32_16x16x32_bf16((a), (b), (c), 0, 0, 0)

__device__ __forceinline__ short f2bf(float f) {  // RNE fp32 -> bf16
  unsigned u = __float_as_uint(f);
  u += 0x7fffu + ((u >> 16) & 1u);
  return (short)(u >> 16);
}

// packed fp32x2 -> bf16x2 (RNE) in one VALU op
__device__ __forceinline__ int cvtpk(float a, float b) {
  int r;
  asm("v_cvt_pk_bf16_f32 %0, %1, %2" : "=v"(r) : "v"(a), "v"(b));
  return r;
}

// async global->LDS, 16B per lane; LDS dest = wave-uniform base + lane*16
__device__ __forceinline__ void glds16(const short* g, short* l) {
  __builtin_amdgcn_global_load_lds(
      (const __attribute__((address_space(1))) void*)g,
      (__attribute__((address_space(3))) void*)l, 16, 0, 0);
}

// ---------- fused fp32 -> bf16 cast (all 9 tensors, one launch) ----------
struct CastSeg { const float* src; short* dst; int n4; };
struct CastArgs { CastSeg seg[9]; int start[10]; };

__global__ __launch_bounds__(256) void castk(CastArgs a) {
  int blk = blockIdx.x;
  int si = 0;
#pragma unroll
  for (int i = 1; i < 9; i++) si += (blk >= a.start[i]);
  int i = (blk - a.start[si]) * 256 + threadIdx.x;
  if (i >= a.seg[si].n4) return;
  float4v f = ((const float4v*)a.seg[si].src)[i];
  short4v o;
  o[0] = f2bf(f[0]); o[1] = f2bf(f[1]); o[2] = f2bf(f[2]); o[3] = f2bf(f[3]);
  ((short4v*)a.seg[si].dst)[i] = o;
}

// ---------- segmented runtime-flag MFMA GEMM (fat-K; gemm_c / gemm_o) ----------
// flags: 1=ROPE, 2=SCALE, 4=V^T out, 8=fp32 out, 16=bn-pair
struct GSeg {
  const short* A;
  const short* W;
  const float* bias0;
  const float* bias1;
  void* outp;
  int lda, ldw, bsplit, ropestart, ldo, ocol, K, flags;
};
struct GArgs { GSeg s[3]; int start[4]; };

__device__ __forceinline__ void gemm_body(const GArgs& ga, const int* __restrict__ pos) {
  int by = blockIdx.y;
  int si = (by >= ga.start[1]) + (by >= ga.start[2]);
  const GSeg sg = ga.s[si];
  int tid = threadIdx.x, w = tid >> 6, lane = tid & 63;
  int quad = lane >> 4, l16 = lane & 15;
  bool ropeF = sg.flags & 1, scaleF = sg.flags & 2;
  bool vtF = sg.flags & 4, f32F = sg.flags & 8, pairF = sg.flags & 16;
  int bm = blockIdx.x * 128;
  int bn = (by - ga.start[si]) * (pairF ? 256 : 128);
  int wm = (w & 1) * 64, wn = (w >> 1) * 64;
  int lda = sg.lda, ldw = sg.ldw;

  __shared__ short At[2][128 * 64];
  __shared__ short Bt[2][128 * 64];

  int srow[4], soff[4];
#pragma unroll
  for (int j = 0; j < 4; j++) {
    int r = w * 32 + j * 8 + (lane >> 3);
    srow[j] = r;
    soff[j] = ((lane & 7) ^ (r & 7)) << 3;
  }
  const short* Ag = sg.A + (size_t)bm * lda;
  const short* Wg = sg.W + (size_t)bn * ldw;

  float4v acc[4][4];
  float4v z = {0.f, 0.f, 0.f, 0.f};
#pragma unroll
  for (int mi = 0; mi < 4; mi++)
#pragma unroll
    for (int ni = 0; ni < 4; ni++) acc[mi][ni] = z;

  auto comp = [&](const short* Ab, const short* Bb) {
#pragma unroll
    for (int ks = 0; ks < 2; ks++) {
      short8 af[4], bf[4];
#pragma unroll
      for (int mi = 0; mi < 4; mi++) {
        int row = wm + mi * 16 + l16;
        af[mi] = *(const short8*)&Ab[(row << 6) + ((((ks << 2) + quad) ^ (row & 7)) << 3)];
      }
#pragma unroll
      for (int ni = 0; ni < 4; ni++) {
        int row = wn + ni * 16 + l16;
        bf[ni] = *(const short8*)&Bb[(row << 6) + ((((ks << 2) + quad) ^ (row & 7)) << 3)];
      }
#pragma unroll
      for (int mi = 0; mi < 4; mi++)
#pragma unroll
        for (int ni = 0; ni < 4; ni++)
          acc[mi][ni] = MFMA16(af[mi], bf[ni], acc[mi][ni]);
    }
  };

  auto epi = [&](int bnX) {
    if (vtF) {
      __syncthreads();
      short* T = &At[0][0];
#pragma unroll
      for (int ni = 0; ni < 4; ni++) {
        int col = wn + ni * 16 + l16;
        float bv = sg.bias0[bnX + col];
#pragma unroll
        for (int mi = 0; mi < 4; mi++) {
          int row0 = wm + mi * 16 + quad * 4;
          int rr = (row0 + ((col & 15) << 3)) & 127;
          short4v ov;
#pragma unroll
          for (int r = 0; r < 4; r++) ov[r] = f2bf(acc[mi][ni][r] + bv);
          *(short4v*)&T[col * 128 + rr] = ov;
        }
      }
      __syncthreads();
      int bidx = bm >> 11, s0 = bm & 2047;
      int sc = tid & 15;
#pragma unroll
      for (int cc = 0; cc < 8; cc++) {
        int c = cc * 16 + (tid >> 4);
        int rr = ((sc + (c & 15)) << 3) & 127;
        short8 v = *(const short8*)&T[c * 128 + rr];
        *(short8*)((short*)sg.outp + ((size_t)(bidx * 1536 + bnX + c)) * 2048 +
                   s0 + (sc << 3)) = v;
      }
      return;
    }
#pragma unroll
    for (int ni = 0; ni < 4; ni++) {
      int col = bnX + wn + ni * 16 + l16;
      float bv = (col < sg.bsplit) ? sg.bias0[col] : sg.bias1[col - sg.bsplit];
      float fr = 0.f;
      bool dorope = ropeF && (col >= sg.ropestart);
      if (dorope) {
        int ri = (col - sg.ropestart) & ~1;
        fr = exp2f((float)ri * (-13.287712379549449f / 768.0f));
      }
#pragma unroll
      for (int mi = 0; mi < 4; mi++) {
        int row0 = bm + wm + mi * 16 + quad * 4;
#pragma unroll
        for (int r = 0; r < 4; r++) {
          int row = row0 + r;
          float v = acc[mi][ni][r] + bv;
          if (ropeF) {
            float pv = __shfl_xor(v, 1, 64);
            if (dorope) {
              float ang = (float)pos[row & 2047] * fr;
              float sn, cs;
              __sincosf(ang, &sn, &cs);
              v = (col & 1) ? (pv * sn + v * cs) : (v * cs - pv * sn);
            }
          }
          if (scaleF) v *= 0.12751743f;  // (1/sqrt(128)) * log2(e)
          if (f32F)
            ((float*)sg.outp)[(size_t)row * sg.ldo + sg.ocol + col] = v;
          else
            ((short*)sg.outp)[(size_t)row * sg.ldo + sg.ocol + col] = f2bf(v);
        }
      }
    }
  };

  int nk = sg.K >> 6;
  {
#pragma unroll
    for (int j = 0; j < 4; j++)
      glds16(Ag + (size_t)srow[j] * lda + soff[j], &At[0][(w * 32 + j * 8) * 64]);
#pragma unroll
    for (int j = 0; j < 4; j++)
      glds16(Wg + (size_t)srow[j] * ldw + soff[j], &Bt[0][(w * 32 + j * 8) * 64]);
    for (int it = 0; it < nk; it++) {
      __syncthreads();
      if (it + 1 < nk) {
        int kt = (it + 1) << 6, nb = (it + 1) & 1;
#pragma unroll
        for (int j = 0; j < 4; j++)
          glds16(Ag + (size_t)srow[j] * lda + kt + soff[j],
                 &At[nb][(w * 32 + j * 8) * 64]);
#pragma unroll
        for (int j = 0; j < 4; j++)
          glds16(Wg + (size_t)srow[j] * ldw + kt + soff[j],
                 &Bt[nb][(w * 32 + j * 8) * 64]);
      }
      comp(At[it & 1], Bt[it & 1]);
    }
    epi(bn);
  }
}

__global__ __launch_bounds__(256, 2) void gemm_c(GArgs ga, const int* __restrict__ pos) {
  gemm_body(ga, pos);
}
__global__ __launch_bounds__(256, 2) void gemm_o(GArgs ga, const int* __restrict__ pos) {
  gemm_body(ga, pos);
}

// ---------- thin-K (K=128) N-streaming GEMM: Q || k_nope || V^T ----------
// Per block: stage A (128 Cm rows, K=128, 32KB) ONCE, then stream 4x 64-row W
// subtiles (16KB) double-buffered -> DMA overlaps MFMA+epilogue (fat-K loop
// discipline applied along N). LDS 80KB -> 2 blocks/CU. Grid (64 m, 15 units):
// units 0-5 Q (256 cols each), 6-8 k_nope, 9-14 V^T. Wave tile 64x32.
__global__ __launch_bounds__(256, 2) void gemm_q(GArgs ga, const int* __restrict__ pos) {
  int by = blockIdx.y;
  int si = (by >= ga.start[1]) + (by >= ga.start[2]);
  const GSeg sg = ga.s[si];
  int tid = threadIdx.x, w = tid >> 6, lane = tid & 63;
  int quad = lane >> 4, l16 = lane & 15;
  bool ropeF = sg.flags & 1, scaleF = sg.flags & 2, vtF = sg.flags & 4;
  int bm = blockIdx.x * 128;
  int bnu = (by - ga.start[si]) * 256;  // segment-local unit base
  int wm = (w & 1) * 64, wn = (w >> 1) * 32;

  __shared__ short At[128 * 128];    // 32KB: 128 rows x K=128
  __shared__ short Bt[2][64 * 128];  // 2x16KB W subtiles
  __shared__ short Tt[64 * 128];     // 16KB transpose scratch (V^T)

  // ---- stage A once: 128 rows x 256B, attention-style XOR chunk swizzle ----
  const short* Ag = sg.A + (size_t)bm * 256;
#pragma unroll
  for (int j = 0; j < 8; j++) {
    int rk = w * 32 + j * 4 + (lane >> 4);
    glds16(Ag + (size_t)rk * 256 + ((l16 ^ (rk & 7)) << 3),
           &At[(w * 32 + j * 4) * 128]);
  }
  const short* Wg0 = sg.W + (size_t)bnu * 128;
  auto stageB = [&](int sub, short* dst) {
    const short* Wg = Wg0 + (size_t)(sub * 64) * 128;
#pragma unroll
    for (int j = 0; j < 4; j++) {
      int rk = w * 16 + j * 4 + (lane >> 4);
      glds16(Wg + (size_t)rk * 128 + ((l16 ^ (rk & 7)) << 3),
             &dst[(w * 16 + j * 4) * 128]);
    }
  };

  float4v acc[4][2];
  float4v z = {0.f, 0.f, 0.f, 0.f};
#pragma unroll
  for (int mi = 0; mi < 4; mi++)
#pragma unroll
    for (int ni = 0; ni < 2; ni++) acc[mi][ni] = z;

  auto comp = [&](const short* Bb) {
#pragma unroll
    for (int ks = 0; ks < 4; ks++) {
      short8 af[4], bf[2];
#pragma unroll
      for (int mi = 0; mi < 4; mi++) {
        int row = wm + mi * 16 + l16;
        af[mi] = *(const short8*)&At[(row << 7) + (((ks * 4 + quad) ^ (row & 7)) << 3)];
      }
#pragma unroll
      for (int ni = 0; ni < 2; ni++) {
        int row = wn + ni * 16 + l16;
        bf[ni] = *(const short8*)&Bb[(row << 7) + (((ks * 4 + quad) ^ (row & 7)) << 3)];
      }
#pragma unroll
      for (int mi = 0; mi < 4; mi++)
#pragma unroll
        for (int ni = 0; ni < 2; ni++)
          acc[mi][ni] = MFMA16(af[mi], bf[ni], acc[mi][ni]);
    }
  };

  auto epi = [&](int bnX) {  // bnX = segment-local col base of this 64-subtile
    if (vtF) {
      __syncthreads();  // prior Tt readers done
#pragma unroll
      for (int ni = 0; ni < 2; ni++) {
        int col = wn + ni * 16 + l16;  // [0,64)
        float bv = sg.bias0[bnX + col];
#pragma unroll
        for (int mi = 0; mi < 4; mi++) {
          int row0 = wm + mi * 16 + quad * 4;
          int rr = (row0 + ((col & 15) << 3)) & 127;
          short4v ov;
#pragma unroll
          for (int r = 0; r < 4; r++) ov[r] = f2bf(acc[mi][ni][r] + bv);
          *(short4v*)&Tt[col * 128 + rr] = ov;
        }
      }
      __syncthreads();
      int bidx = bm >> 11, s0 = bm & 2047;
      int sc = tid & 15;
#pragma unroll
      for (int cc = 0; cc < 4; cc++) {
        int c = cc * 16 + (tid >> 4);
        int rr = ((sc + (c & 15)) << 3) & 127;
        short8 v = *(const short8*)&Tt[c * 128 + rr];
        *(short8*)((short*)sg.outp + ((size_t)(bidx * 1536 + bnX + c)) * 2048 +
                   s0 + (sc << 3)) = v;
      }
      return;
    }
#pragma unroll
    for (int ni = 0; ni < 2; ni++) {
      int col = bnX + wn + ni * 16 + l16;
      float bv = (col < sg.bsplit) ? sg.bias0[col] : sg.bias1[col - sg.bsplit];
      float fr = 0.f;
      bool dorope = ropeF && (col >= sg.ropestart);
      if (dorope) {
        int ri = (col - sg.ropestart) & ~1;
        fr = exp2f((float)ri * (-13.287712379549449f / 768.0f));
      }
#pragma unroll
      for (int mi = 0; mi < 4; mi++) {
        int row0 = bm + wm + mi * 16 + quad * 4;
#pragma unroll
        for (int r = 0; r < 4; r++) {
          int row = row0 + r;
          float v = acc[mi][ni][r] + bv;
          if (ropeF) {
            float pv = __shfl_xor(v, 1, 64);
            if (dorope) {
              float ang = (float)pos[row & 2047] * fr;
              float sn, cs;
              __sincosf(ang, &sn, &cs);
              v = (col & 1) ? (pv * sn + v * cs) : (v * cs - pv * sn);
            }
          }
          if (scaleF) v *= 0.12751743f;
          ((short*)sg.outp)[(size_t)row * sg.ldo + sg.ocol + col] = f2bf(v);
        }
      }
    }
  };

  stageB(0, Bt[0]);
  __syncthreads();  // drains A + B0
  for (int t = 0; t < 4; t++) {
    if (t) __syncthreads();  // drains B[t] DMA; all waves done reading B[t-2]'s buffer
    if (t + 1 < 4) stageB(t + 1, Bt[(t + 1) & 1]);  // overlaps comp+epi below
    comp(Bt[t & 1]);
    epi(bnu + t * 64);
#pragma unroll
    for (int mi = 0; mi < 4; mi++)
#pragma unroll
      for (int ni = 0; ni < 2; ni++) acc[mi][ni] = z;
  }
}

// ---------- causal flash attention: 128-q blocks, 32 q/wave, no-max softmax ----
// grid 768 (1-D, global LPT order), 256 thr. KVBLK=64 (R3/R7-verified 85us).
__global__ __launch_bounds__(256, 2) void mla_attn(const short* __restrict__ Q,
                                                   const short* __restrict__ K,
                                                   const short* __restrict__ Vt,
                                                   short* __restrict__ O) {
  const int ld = 1536, SEQ = 2048;
  int tid = threadIdx.x, w = tid >> 6, lane = tid & 63;
  int quad = lane >> 4, l16 = lane & 15;
  int o = (int)blockIdx.x;
  int rank = o / 48;
  int g = o - rank * 48;
  int qt = (15 - rank) * 128;
  int hh = g % 12, b = g / 12;
  int qw = qt + w * 32;

  __shared__ short Kt[2][64 * 128];
  __shared__ short Vl[2][128 * 64];
  __shared__ short Pm[4][32 * 64];
  char* pwB = (char*)Pm[w];

  int kgo[4], vgo[4];
#pragma unroll
  for (int j = 0; j < 4; j++) {
    int rk = (w * 4 + j) * 4 + (lane >> 4);
    kgo[j] = rk * ld + (((lane & 15) ^ (rk & 7)) << 3);
    int rv = (w * 4 + j) * 8 + (lane >> 3);
    vgo[j] = rv * SEQ + (((lane & 7) ^ (rv & 7)) << 3);
  }
  const short* Kg = K + (size_t)b * SEQ * ld + hh * 128;
  const short* Vg = Vt + (size_t)(b * 12 + hh) * 128 * SEQ;

  short8 qf[2][4];
  {
    const short* Qg = Q + (size_t)(b * SEQ + qw + l16) * ld + hh * 128 + quad * 8;
#pragma unroll
    for (int nf = 0; nf < 2; nf++)
#pragma unroll
      for (int ks = 0; ks < 4; ks++)
        qf[nf][ks] = *(const short8*)(Qg + (size_t)nf * 16 * ld + ks * 32);
  }

  // ---- loop-invariant LDS byte offsets ----
  int koff[4][4], voff[2][8], pfo[2][2], pwo[2][4];
#pragma unroll
  for (int ks = 0; ks < 4; ks++)
#pragma unroll
    for (int mf = 0; mf < 4; mf++) {
      int row = mf * 16 + l16;
      koff[ks][mf] = row * 256 + ((((ks << 2) + quad) ^ (row & 7)) << 4);
    }
#pragma unroll
  for (int t = 0; t < 2; t++) {
#pragma unroll
    for (int df = 0; df < 8; df++) {
      int vr = df * 16 + l16;
      voff[t][df] = vr * 128 + ((((t << 2) + quad) ^ (vr & 7)) << 4);
    }
#pragma unroll
    for (int mq = 0; mq < 2; mq++)
      pfo[t][mq] = (mq * 16 + l16) * 128 + ((((t << 2) + quad) ^ (l16 & 7)) << 4);
#pragma unroll
    for (int mf = 0; mf < 4; mf++) {
      int p = (mf * 2 + (quad >> 1)) ^ (l16 & 7);
      pwo[t][mf] = (t * 16 + l16) * 128 + (p << 4) + ((quad & 1) << 3);
    }
  }

  float4v z = {0.f, 0.f, 0.f, 0.f};
  float4v oacc[2][8];
#pragma unroll
  for (int mq = 0; mq < 2; mq++)
#pragma unroll
    for (int df = 0; df < 8; df++) oacc[mq][df] = z;
  float l_i[2] = {0.f, 0.f};

#pragma unroll
  for (int j = 0; j < 4; j++) glds16(Kg + kgo[j], &Kt[0][(w * 4 + j) * 512]);
#pragma unroll
  for (int j = 0; j < 4; j++) glds16(Vg + vgo[j], &Vl[0][(w * 4 + j) * 512]);

  int ntiles = (qt >> 6) + 2;  // always even

#define ATTN_TILE(IT, NB, NB1)                                                 \
  do {                                                                         \
    int kt = (IT) << 6;                                                        \
    __syncthreads();                                                           \
    if ((IT) + 1 < ntiles) {                                                   \
      const short* kn = Kg + (size_t)(kt + 64) * ld;                           \
      const short* vn = Vg + (kt + 64);                                        \
      _Pragma("unroll") for (int j = 0; j < 4; j++)                            \
          glds16(kn + kgo[j], &Kt[NB1][(w * 4 + j) * 512]);                    \
      _Pragma("unroll") for (int j = 0; j < 4; j++)                            \
          glds16(vn + vgo[j], &Vl[NB1][(w * 4 + j) * 512]);                    \
    }                                                                          \
    if (kt <= qw + 31) {                                                       \
      const char* Kb = (const char*)Kt[NB];                                    \
      const char* Vb = (const char*)Vl[NB];                                    \
      float4v sf[4][2];                                                        \
      __builtin_amdgcn_s_setprio(1);                                           \
      _Pragma("unroll") for (int mf = 0; mf < 4; mf++) {                       \
        short8 a = *(const short8*)(Kb + koff[0][mf]);                         \
        sf[mf][0] = MFMA16(a, qf[0][0], z);                                    \
        sf[mf][1] = MFMA16(a, qf[1][0], z);                                    \
      }                                                                        \
      _Pragma("unroll") for (int ks = 1; ks < 4; ks++) {                       \
        _Pragma("unroll") for (int mf = 0; mf < 4; mf++) {                     \
          short8 a = *(const short8*)(Kb + koff[ks][mf]);                      \
          sf[mf][0] = MFMA16(a, qf[0][ks], sf[mf][0]);                         \
          sf[mf][1] = MFMA16(a, qf[1][ks], sf[mf][1]);                         \
        }                                                                      \
      }                                                                        \
      __builtin_amdgcn_s_setprio(0);                                           \
      if (kt + 63 > qw) {                                                      \
        _Pragma("unroll") for (int mf = 0; mf < 4; mf++) {                     \
          int key = kt + mf * 16 + quad * 4;                                   \
          _Pragma("unroll") for (int nf = 0; nf < 2; nf++) {                   \
            int q = qw + nf * 16 + l16;                                        \
            _Pragma("unroll") for (int r = 0; r < 4; r++)                      \
                if (key + r > q) sf[mf][nf][r] = -3e38f;                       \
          }                                                                    \
        }                                                                      \
      }                                                                        \
      _Pragma("unroll") for (int nf = 0; nf < 2; nf++) {                       \
        float ps = 0.f;                                                        \
        _Pragma("unroll") for (int mf = 0; mf < 4; mf++)                       \
            _Pragma("unroll") for (int r = 0; r < 4; r++) {                    \
          float e = exp2f(sf[mf][nf][r]);                                      \
          sf[mf][nf][r] = e;                                                   \
          ps += e;                                                             \
        }                                                                      \
        l_i[nf] += ps;                                                         \
        _Pragma("unroll") for (int mf = 0; mf < 4; mf++) {                     \
          int2v pk;                                                            \
          pk[0] = cvtpk(sf[mf][nf][0], sf[mf][nf][1]);                         \
          pk[1] = cvtpk(sf[mf][nf][2], sf[mf][nf][3]);                         \
          *(int2v*)(pwB + pwo[nf][mf]) = pk;                                   \
        }                                                                      \
      }                                                                        \
      __builtin_amdgcn_s_setprio(1);                                           \
      _Pragma("unroll") for (int t = 0; t < 2; t++) {                          \
        short8 pf0 = *(const short8*)(pwB + pfo[t][0]);                        \
        short8 pf1 = *(const short8*)(pwB + pfo[t][1]);                        \
        _Pragma("unroll") for (int df = 0; df < 8; df++) {                     \
          short8 vf = *(const short8*)(Vb + voff[t][df]);                      \
          oacc[0][df] = MFMA16(pf0, vf, oacc[0][df]);                          \
          oacc[1][df] = MFMA16(pf1, vf, oacc[1][df]);                          \
        }                                                                      \
      }                                                                        \
      __builtin_amdgcn_s_setprio(0);                                           \
    }                                                                          \
  } while (0)

  for (int it = 0; it < ntiles; it += 2) {
    ATTN_TILE(it, 0, 1);
    ATTN_TILE(it + 1, 1, 0);
  }
#undef ATTN_TILE

  // ---- epilogue: reduce l across quads, scale, store ----
  short* Og = O + (size_t)(b * SEQ + qw) * ld + hh * 128;
#pragma unroll
  for (int mq = 0; mq < 2; mq++) {
    float l = l_i[mq];
    l += __shfl_xor(l, 16, 64);
    l += __shfl_xor(l, 32, 64);
    float linv = 1.0f / l;
    float lb[4];
#pragma unroll
    for (int r = 0; r < 4; r++) lb[r] = __shfl(linv, (quad << 2) + r, 64);
#pragma unroll
    for (int df = 0; df < 8; df++)
#pragma unroll
      for (int r = 0; r < 4; r++)
        Og[(size_t)(mq * 16 + (quad << 2) + r) * ld + df * 16 + l16] =
            f2bf(oacc[mq][df][r] * lb[r]);
  }
}

// ---------- launcher ----------
extern "C" void kernel_launch(void* const* d_in, const int* in_sizes, int n_in,
                              void* d_out, int out_size, void* d_ws, size_t ws_size,
                              hipStream_t stream) {
  const int S = 2048, DM = 768, DL = 128, HD = 1536;
  const int M = 4 * S;  // 8192
  const int BIG = 1 << 28;

  const float* x = (const float*)d_in[0];
  const int* pos = (const int*)d_in[1];
  const float* W_dkv = (const float*)d_in[2];
  const float* b_dkv = (const float*)d_in[3];
  const float* W_dq = (const float*)d_in[4];
  const float* b_dq = (const float*)d_in[5];
  const float* W_uk_nope = (const float*)d_in[6];
  const float* b_uk_nope = (const float*)d_in[7];
  const float* W_uv = (const float*)d_in[8];
  const float* b_uv = (const float*)d_in[9];
  const float* W_uq_nope = (const float*)d_in[10];
  const float* b_uq_nope = (const float*)d_in[11];
  const float* W_uq_rope = (const float*)d_in[12];
  const float* b_uq_rope = (const float*)d_in[13];
  const float* W_uk_rope = (const float*)d_in[14];
  const float* b_uk_rope = (const float*)d_in[15];
  const float* W_o = (const float*)d_in[16];
  const float* b_o = (const float*)d_in[17];

  char* p = (char*)d_ws;
  size_t off = 0;
  auto take = [&](size_t nelem) -> short* {
    short* r = (short*)(p + off);
    off += (nelem * 2 + 255) & ~(size_t)255;
    return r;
  };
  short* xb = take((size_t)M * DM);
  short* Wdq = take(DL * DM);
  short* Wdkv = take(DL * DM);
  short* Wuqnope = take(768 * DL);
  short* Wuqrope = take(768 * DL);
  short* Wuknope = take(768 * DL);
  short* Wuv = take(1536 * DL);
  short* Wukrope = take(768 * DM);
  short* Wo = take(768 * 1536);
  short* Cm = take((size_t)M * 256);  // [C_q | C_kv]
  short* Qm = take((size_t)M * HD);
  short* Km = take((size_t)M * HD);
  short* Vtm = take((size_t)M * HD);  // V^T: [b][h*128+d][s]
  short* Om = take((size_t)M * HD);
  if (off > ws_size) return;

  CastArgs ca;
  const float* srcs[9] = {x, W_dq, W_dkv, W_uq_nope, W_uq_rope, W_uk_nope, W_uv, W_uk_rope, W_o};
  short* dsts[9] = {xb, Wdq, Wdkv, Wuqnope, Wuqrope, Wuknope, Wuv, Wukrope, Wo};
  int ns[9] = {M * DM, DL * DM, DL * DM, 768 * DL, 768 * DL, 768 * DL, 1536 * DL, 768 * DM, 768 * 1536};
  ca.start[0] = 0;
  for (int i = 0; i < 9; i++) {
    ca.seg[i].src = srcs[i];
    ca.seg[i].dst = dsts[i];
    ca.seg[i].n4 = ns[i] / 4;
    ca.start[i + 1] = ca.start[i] + (ca.seg[i].n4 + 255) / 256;
  }
  castk<<<dim3(ca.start[9]), dim3(256), 0, stream>>>(ca);

  // ---- launch 1: C (N=256,K=768) || rope(k_rope) (N=768,K=768) ----
  GArgs g1;
  g1.s[0].A = xb;   g1.s[0].W = Wdq;      g1.s[0].bias0 = b_dq;      g1.s[0].bias1 = b_dkv;
  g1.s[0].outp = Cm; g1.s[0].lda = DM; g1.s[0].ldw = DM; g1.s[0].bsplit = 128;
  g1.s[0].ropestart = 0; g1.s[0].ldo = 256; g1.s[0].ocol = 0; g1.s[0].K = DM; g1.s[0].flags = 0;
  g1.s[1].A = xb;   g1.s[1].W = Wukrope;  g1.s[1].bias0 = b_uk_rope; g1.s[1].bias1 = b_uk_rope;
  g1.s[1].outp = Km; g1.s[1].lda = DM; g1.s[1].ldw = DM; g1.s[1].bsplit = BIG;
  g1.s[1].ropestart = 0; g1.s[1].ldo = HD; g1.s[1].ocol = 768; g1.s[1].K = DM; g1.s[1].flags = 1;
  g1.s[2] = g1.s[1];
  g1.start[0] = 0; g1.start[1] = 2; g1.start[2] = 8; g1.start[3] = 8;
  gemm_c<<<dim3(M / 128, 8), dim3(256), 0, stream>>>(g1, pos);

  // ---- launch 2 (N-streaming thin-K): Q || k_nope || V^T ----
  GArgs g2;
  g2.s[0].A = Cm;   g2.s[0].W = Wuqnope;  g2.s[0].bias0 = b_uq_nope; g2.s[0].bias1 = b_uq_rope;
  g2.s[0].outp = Qm; g2.s[0].lda = 256; g2.s[0].ldw = DL; g2.s[0].bsplit = 768;
  g2.s[0].ropestart = 768; g2.s[0].ldo = HD; g2.s[0].ocol = 0; g2.s[0].K = DL;
  g2.s[0].flags = 1 | 2;
  g2.s[1].A = Cm + 128; g2.s[1].W = Wuknope; g2.s[1].bias0 = b_uk_nope; g2.s[1].bias1 = b_uk_nope;
  g2.s[1].outp = Km; g2.s[1].lda = 256; g2.s[1].ldw = DL; g2.s[1].bsplit = BIG;
  g2.s[1].ropestart = 0; g2.s[1].ldo = HD; g2.s[1].ocol = 0; g2.s[1].K = DL;
  g2.s[1].flags = 0;
  g2.s[2].A = Cm + 128; g2.s[2].W = Wuv;   g2.s[2].bias0 = b_uv;      g2.s[2].bias1 = b_uv;
  g2.s[2].outp = Vtm; g2.s[2].lda = 256; g2.s[2].ldw = DL; g2.s[2].bsplit = BIG;
  g2.s[2].ropestart = 0; g2.s[2].ldo = 0; g2.s[2].ocol = 0; g2.s[2].K = DL;
  g2.s[2].flags = 4;
  g2.start[0] = 0; g2.start[1] = 6; g2.start[2] = 9; g2.start[3] = 15;
  gemm_q<<<dim3(M / 128, 15), dim3(256), 0, stream>>>(g2, pos);

  // ---- attention: 768 blocks, global longest-first (LPT) order ----
  mla_attn<<<dim3(768), dim3(256), 0, stream>>>(Qm, Km, Vtm, Om);

  // ---- launch 3: out = O @ W_o^T + b_o (N=768, K=1536, fp32 out) ----
  GArgs g3;
  g3.s[0].A = Om;   g3.s[0].W = Wo;       g3.s[0].bias0 = b_o;       g3.s[0].bias1 = b_o;
  g3.s[0].outp = d_out; g3.s[0].lda = HD; g3.s[0].ldw = HD; g3.s[0].bsplit = BIG;
  g3.s[0].ropestart = 0; g3.s[0].ldo = 768; g3.s[0].ocol = 0; g3.s[0].K = HD; g3.s[0].flags = 8;
  g3.s[1] = g3.s[0];
  g3.s[2] = g3.s[0];
  g3.start[0] = 0; g3.start[1] = 6; g3.start[2] = 6; g3.start[3] = 6;
  gemm_o<<<dim3(M / 128, 6), dim3(256), 0, stream>>>(g3, pos);
}

// Round 9
// 280.036 us; speedup vs baseline: 1.5650x; 1.0551x over previous
//
#include <hip/hip_runtime.h>

// ---------- types ----------
typedef __attribute__((ext_vector_type(8))) short short8;   // 8 x bf16
typedef __attribute__((ext_vector_type(4))) short short4v;  // 4 x bf16
typedef __attribute__((ext_vector_type(2))) int int2v;
typedef __attribute__((ext_vector_type(4))) float float4v;

#define MFMA16(a, b, c) __builtin_amdgcn_mfma_f32_16x16x32_bf16((a), (b), (c), 0, 0, 0)

__device__ __forceinline__ short f2bf(float f) {  // RNE fp32 -> bf16
  unsigned u = __float_as_uint(f);
  u += 0x7fffu + ((u >> 16) & 1u);
  return (short)(u >> 16);
}

// packed fp32x2 -> bf16x2 (RNE) in one VALU op
__device__ __forceinline__ int cvtpk(float a, float b) {
  int r;
  asm("v_cvt_pk_bf16_f32 %0, %1, %2" : "=v"(r) : "v"(a), "v"(b));
  return r;
}

// async global->LDS, 16B per lane; LDS dest = wave-uniform base + lane*16
__device__ __forceinline__ void glds16(const short* g, short* l) {
  __builtin_amdgcn_global_load_lds(
      (const __attribute__((address_space(1))) void*)g,
      (__attribute__((address_space(3))) void*)l, 16, 0, 0);
}

// ---------- fused fp32 -> bf16 cast (all 9 tensors, one launch) ----------
struct CastSeg { const float* src; short* dst; int n4; };
struct CastArgs { CastSeg seg[9]; int start[10]; };

__global__ __launch_bounds__(256) void castk(CastArgs a) {
  int blk = blockIdx.x;
  int si = 0;
#pragma unroll
  for (int i = 1; i < 9; i++) si += (blk >= a.start[i]);
  int i = (blk - a.start[si]) * 256 + threadIdx.x;
  if (i >= a.seg[si].n4) return;
  float4v f = ((const float4v*)a.seg[si].src)[i];
  short4v o;
  o[0] = f2bf(f[0]); o[1] = f2bf(f[1]); o[2] = f2bf(f[2]); o[3] = f2bf(f[3]);
  ((short4v*)a.seg[si].dst)[i] = o;
}

// ---------- segmented runtime-flag MFMA GEMM (fat-K 128x128; gemm_c) ----------
// flags: 1=ROPE, 2=SCALE, 4=V^T out, 8=fp32 out, 16=bn-pair
struct GSeg {
  const short* A;
  const short* W;
  const float* bias0;
  const float* bias1;
  void* outp;
  int lda, ldw, bsplit, ropestart, ldo, ocol, K, flags;
};
struct GArgs { GSeg s[3]; int start[4]; };

__device__ __forceinline__ void gemm_body(const GArgs& ga, const int* __restrict__ pos) {
  int by = blockIdx.y;
  int si = (by >= ga.start[1]) + (by >= ga.start[2]);
  const GSeg sg = ga.s[si];
  int tid = threadIdx.x, w = tid >> 6, lane = tid & 63;
  int quad = lane >> 4, l16 = lane & 15;
  bool ropeF = sg.flags & 1, scaleF = sg.flags & 2;
  bool vtF = sg.flags & 4, f32F = sg.flags & 8, pairF = sg.flags & 16;
  int bm = blockIdx.x * 128;
  int bn = (by - ga.start[si]) * (pairF ? 256 : 128);
  int wm = (w & 1) * 64, wn = (w >> 1) * 64;
  int lda = sg.lda, ldw = sg.ldw;

  __shared__ short At[2][128 * 64];
  __shared__ short Bt[2][128 * 64];

  int srow[4], soff[4];
#pragma unroll
  for (int j = 0; j < 4; j++) {
    int r = w * 32 + j * 8 + (lane >> 3);
    srow[j] = r;
    soff[j] = ((lane & 7) ^ (r & 7)) << 3;
  }
  const short* Ag = sg.A + (size_t)bm * lda;
  const short* Wg = sg.W + (size_t)bn * ldw;

  float4v acc[4][4];
  float4v z = {0.f, 0.f, 0.f, 0.f};
#pragma unroll
  for (int mi = 0; mi < 4; mi++)
#pragma unroll
    for (int ni = 0; ni < 4; ni++) acc[mi][ni] = z;

  auto comp = [&](const short* Ab, const short* Bb) {
#pragma unroll
    for (int ks = 0; ks < 2; ks++) {
      short8 af[4], bf[4];
#pragma unroll
      for (int mi = 0; mi < 4; mi++) {
        int row = wm + mi * 16 + l16;
        af[mi] = *(const short8*)&Ab[(row << 6) + ((((ks << 2) + quad) ^ (row & 7)) << 3)];
      }
#pragma unroll
      for (int ni = 0; ni < 4; ni++) {
        int row = wn + ni * 16 + l16;
        bf[ni] = *(const short8*)&Bb[(row << 6) + ((((ks << 2) + quad) ^ (row & 7)) << 3)];
      }
#pragma unroll
      for (int mi = 0; mi < 4; mi++)
#pragma unroll
        for (int ni = 0; ni < 4; ni++)
          acc[mi][ni] = MFMA16(af[mi], bf[ni], acc[mi][ni]);
    }
  };

  auto epi = [&](int bnX) {
    if (vtF) {
      __syncthreads();
      short* T = &At[0][0];
#pragma unroll
      for (int ni = 0; ni < 4; ni++) {
        int col = wn + ni * 16 + l16;
        float bv = sg.bias0[bnX + col];
#pragma unroll
        for (int mi = 0; mi < 4; mi++) {
          int row0 = wm + mi * 16 + quad * 4;
          int rr = (row0 + ((col & 15) << 3)) & 127;
          short4v ov;
#pragma unroll
          for (int r = 0; r < 4; r++) ov[r] = f2bf(acc[mi][ni][r] + bv);
          *(short4v*)&T[col * 128 + rr] = ov;
        }
      }
      __syncthreads();
      int bidx = bm >> 11, s0 = bm & 2047;
      int sc = tid & 15;
#pragma unroll
      for (int cc = 0; cc < 8; cc++) {
        int c = cc * 16 + (tid >> 4);
        int rr = ((sc + (c & 15)) << 3) & 127;
        short8 v = *(const short8*)&T[c * 128 + rr];
        *(short8*)((short*)sg.outp + ((size_t)(bidx * 1536 + bnX + c)) * 2048 +
                   s0 + (sc << 3)) = v;
      }
      return;
    }
#pragma unroll
    for (int ni = 0; ni < 4; ni++) {
      int col = bnX + wn + ni * 16 + l16;
      float bv = (col < sg.bsplit) ? sg.bias0[col] : sg.bias1[col - sg.bsplit];
      float fr = 0.f;
      bool dorope = ropeF && (col >= sg.ropestart);
      if (dorope) {
        int ri = (col - sg.ropestart) & ~1;
        fr = exp2f((float)ri * (-13.287712379549449f / 768.0f));
      }
#pragma unroll
      for (int mi = 0; mi < 4; mi++) {
        int row0 = bm + wm + mi * 16 + quad * 4;
#pragma unroll
        for (int r = 0; r < 4; r++) {
          int row = row0 + r;
          float v = acc[mi][ni][r] + bv;
          if (ropeF) {
            float pv = __shfl_xor(v, 1, 64);
            if (dorope) {
              float ang = (float)pos[row & 2047] * fr;
              float sn, cs;
              __sincosf(ang, &sn, &cs);
              v = (col & 1) ? (pv * sn + v * cs) : (v * cs - pv * sn);
            }
          }
          if (scaleF) v *= 0.12751743f;  // (1/sqrt(128)) * log2(e)
          if (f32F)
            ((float*)sg.outp)[(size_t)row * sg.ldo + sg.ocol + col] = v;
          else
            ((short*)sg.outp)[(size_t)row * sg.ldo + sg.ocol + col] = f2bf(v);
        }
      }
    }
  };

  int nk = sg.K >> 6;
  {
#pragma unroll
    for (int j = 0; j < 4; j++)
      glds16(Ag + (size_t)srow[j] * lda + soff[j], &At[0][(w * 32 + j * 8) * 64]);
#pragma unroll
    for (int j = 0; j < 4; j++)
      glds16(Wg + (size_t)srow[j] * ldw + soff[j], &Bt[0][(w * 32 + j * 8) * 64]);
    for (int it = 0; it < nk; it++) {
      __syncthreads();
      if (it + 1 < nk) {
        int kt = (it + 1) << 6, nb = (it + 1) & 1;
#pragma unroll
        for (int j = 0; j < 4; j++)
          glds16(Ag + (size_t)srow[j] * lda + kt + soff[j],
                 &At[nb][(w * 32 + j * 8) * 64]);
#pragma unroll
        for (int j = 0; j < 4; j++)
          glds16(Wg + (size_t)srow[j] * ldw + kt + soff[j],
                 &Bt[nb][(w * 32 + j * 8) * 64]);
      }
      comp(At[it & 1], Bt[it & 1]);
    }
    epi(bn);
  }
}

__global__ __launch_bounds__(256, 2) void gemm_c(GArgs ga, const int* __restrict__ pos) {
  gemm_body(ga, pos);
}

// ---------- gemm_o: fat-K 128x64 tiles, 48KB LDS -> 3 blocks/CU ----------
// out = O @ Wo^T + b_o, fp32. Grid (64 m, 12 n) = 768 blocks = exactly 3/CU
// (R8's 128x128 gave 384 blocks = 1.5/CU: half the CUs idle in round 2, weak
// latency hiding). BK stays 64 (R4/R5 lesson: never shrink K amortization).
__global__ __launch_bounds__(256, 3) void gemm_o(GArgs ga, const int* __restrict__ pos) {
  const GSeg sg = ga.s[0];
  int tid = threadIdx.x, w = tid >> 6, lane = tid & 63;
  int quad = lane >> 4, l16 = lane & 15;
  int bm = blockIdx.x * 128, bn = blockIdx.y * 64;
  int wm = (w & 1) * 64, wn = (w >> 1) * 32;
  int lda = sg.lda, ldw = sg.ldw;

  __shared__ short At[2][128 * 64];  // 32KB
  __shared__ short Bt[2][64 * 64];   // 16KB

  int sra[4], sofa[4], srb[2], sofb[2];
#pragma unroll
  for (int j = 0; j < 4; j++) {
    int r = w * 32 + j * 8 + (lane >> 3);
    sra[j] = r;
    sofa[j] = ((lane & 7) ^ (r & 7)) << 3;
  }
#pragma unroll
  for (int j = 0; j < 2; j++) {
    int r = w * 16 + j * 8 + (lane >> 3);
    srb[j] = r;
    sofb[j] = ((lane & 7) ^ (r & 7)) << 3;
  }
  const short* Ag = sg.A + (size_t)bm * lda;
  const short* Wg = sg.W + (size_t)bn * ldw;

  float4v acc[4][2];
  float4v z = {0.f, 0.f, 0.f, 0.f};
#pragma unroll
  for (int mi = 0; mi < 4; mi++)
#pragma unroll
    for (int ni = 0; ni < 2; ni++) acc[mi][ni] = z;

  auto stage = [&](int kt, int nb) {
#pragma unroll
    for (int j = 0; j < 4; j++)
      glds16(Ag + (size_t)sra[j] * lda + kt + sofa[j], &At[nb][(w * 32 + j * 8) * 64]);
#pragma unroll
    for (int j = 0; j < 2; j++)
      glds16(Wg + (size_t)srb[j] * ldw + kt + sofb[j], &Bt[nb][(w * 16 + j * 8) * 64]);
  };

  auto comp = [&](const short* Ab, const short* Bb) {
#pragma unroll
    for (int ks = 0; ks < 2; ks++) {
      short8 af[4], bf[2];
#pragma unroll
      for (int mi = 0; mi < 4; mi++) {
        int row = wm + mi * 16 + l16;
        af[mi] = *(const short8*)&Ab[(row << 6) + ((((ks << 2) + quad) ^ (row & 7)) << 3)];
      }
#pragma unroll
      for (int ni = 0; ni < 2; ni++) {
        int row = wn + ni * 16 + l16;
        bf[ni] = *(const short8*)&Bb[(row << 6) + ((((ks << 2) + quad) ^ (row & 7)) << 3)];
      }
#pragma unroll
      for (int mi = 0; mi < 4; mi++)
#pragma unroll
        for (int ni = 0; ni < 2; ni++)
          acc[mi][ni] = MFMA16(af[mi], bf[ni], acc[mi][ni]);
    }
  };

  int nk = sg.K >> 6;  // 24
  stage(0, 0);
  for (int it = 0; it < nk; it++) {
    __syncthreads();
    if (it + 1 < nk) stage((it + 1) << 6, (it + 1) & 1);
    comp(At[it & 1], Bt[it & 1]);
  }
  // fp32 epilogue
#pragma unroll
  for (int ni = 0; ni < 2; ni++) {
    int col = bn + wn + ni * 16 + l16;
    float bv = sg.bias0[col];
#pragma unroll
    for (int mi = 0; mi < 4; mi++) {
      int row0 = bm + wm + mi * 16 + quad * 4;
#pragma unroll
      for (int r = 0; r < 4; r++)
        ((float*)sg.outp)[(size_t)(row0 + r) * sg.ldo + col] = acc[mi][ni][r] + bv;
    }
  }
}

// ---------- thin-K (K=128) N-streaming GEMM: Q || k_nope || V^T ----------
// Per block: stage A (128 Cm rows, K=128, 32KB) ONCE, then stream 4x 64-row W
// subtiles (16KB) double-buffered -> DMA overlaps MFMA+epilogue. LDS 80KB.
__global__ __launch_bounds__(256, 2) void gemm_q(GArgs ga, const int* __restrict__ pos) {
  int by = blockIdx.y;
  int si = (by >= ga.start[1]) + (by >= ga.start[2]);
  const GSeg sg = ga.s[si];
  int tid = threadIdx.x, w = tid >> 6, lane = tid & 63;
  int quad = lane >> 4, l16 = lane & 15;
  bool ropeF = sg.flags & 1, scaleF = sg.flags & 2, vtF = sg.flags & 4;
  int bm = blockIdx.x * 128;
  int bnu = (by - ga.start[si]) * 256;  // segment-local unit base
  int wm = (w & 1) * 64, wn = (w >> 1) * 32;

  __shared__ short At[128 * 128];    // 32KB: 128 rows x K=128
  __shared__ short Bt[2][64 * 128];  // 2x16KB W subtiles
  __shared__ short Tt[64 * 128];     // 16KB transpose scratch (V^T)

  // ---- stage A once: 128 rows x 256B, attention-style XOR chunk swizzle ----
  const short* Ag = sg.A + (size_t)bm * 256;
#pragma unroll
  for (int j = 0; j < 8; j++) {
    int rk = w * 32 + j * 4 + (lane >> 4);
    glds16(Ag + (size_t)rk * 256 + ((l16 ^ (rk & 7)) << 3),
           &At[(w * 32 + j * 4) * 128]);
  }
  const short* Wg0 = sg.W + (size_t)bnu * 128;
  auto stageB = [&](int sub, short* dst) {
    const short* Wg = Wg0 + (size_t)(sub * 64) * 128;
#pragma unroll
    for (int j = 0; j < 4; j++) {
      int rk = w * 16 + j * 4 + (lane >> 4);
      glds16(Wg + (size_t)rk * 128 + ((l16 ^ (rk & 7)) << 3),
             &dst[(w * 16 + j * 4) * 128]);
    }
  };

  float4v acc[4][2];
  float4v z = {0.f, 0.f, 0.f, 0.f};
#pragma unroll
  for (int mi = 0; mi < 4; mi++)
#pragma unroll
    for (int ni = 0; ni < 2; ni++) acc[mi][ni] = z;

  auto comp = [&](const short* Bb) {
#pragma unroll
    for (int ks = 0; ks < 4; ks++) {
      short8 af[4], bf[2];
#pragma unroll
      for (int mi = 0; mi < 4; mi++) {
        int row = wm + mi * 16 + l16;
        af[mi] = *(const short8*)&At[(row << 7) + (((ks * 4 + quad) ^ (row & 7)) << 3)];
      }
#pragma unroll
      for (int ni = 0; ni < 2; ni++) {
        int row = wn + ni * 16 + l16;
        bf[ni] = *(const short8*)&Bb[(row << 7) + (((ks * 4 + quad) ^ (row & 7)) << 3)];
      }
#pragma unroll
      for (int mi = 0; mi < 4; mi++)
#pragma unroll
        for (int ni = 0; ni < 2; ni++)
          acc[mi][ni] = MFMA16(af[mi], bf[ni], acc[mi][ni]);
    }
  };

  auto epi = [&](int bnX) {  // bnX = segment-local col base of this 64-subtile
    if (vtF) {
      __syncthreads();  // prior Tt readers done
#pragma unroll
      for (int ni = 0; ni < 2; ni++) {
        int col = wn + ni * 16 + l16;  // [0,64)
        float bv = sg.bias0[bnX + col];
#pragma unroll
        for (int mi = 0; mi < 4; mi++) {
          int row0 = wm + mi * 16 + quad * 4;
          int rr = (row0 + ((col & 15) << 3)) & 127;
          short4v ov;
#pragma unroll
          for (int r = 0; r < 4; r++) ov[r] = f2bf(acc[mi][ni][r] + bv);
          *(short4v*)&Tt[col * 128 + rr] = ov;
        }
      }
      __syncthreads();
      int bidx = bm >> 11, s0 = bm & 2047;
      int sc = tid & 15;
#pragma unroll
      for (int cc = 0; cc < 4; cc++) {
        int c = cc * 16 + (tid >> 4);
        int rr = ((sc + (c & 15)) << 3) & 127;
        short8 v = *(const short8*)&Tt[c * 128 + rr];
        *(short8*)((short*)sg.outp + ((size_t)(bidx * 1536 + bnX + c)) * 2048 +
                   s0 + (sc << 3)) = v;
      }
      return;
    }
#pragma unroll
    for (int ni = 0; ni < 2; ni++) {
      int col = bnX + wn + ni * 16 + l16;
      float bv = (col < sg.bsplit) ? sg.bias0[col] : sg.bias1[col - sg.bsplit];
      float fr = 0.f;
      bool dorope = ropeF && (col >= sg.ropestart);
      if (dorope) {
        int ri = (col - sg.ropestart) & ~1;
        fr = exp2f((float)ri * (-13.287712379549449f / 768.0f));
      }
#pragma unroll
      for (int mi = 0; mi < 4; mi++) {
        int row0 = bm + wm + mi * 16 + quad * 4;
#pragma unroll
        for (int r = 0; r < 4; r++) {
          int row = row0 + r;
          float v = acc[mi][ni][r] + bv;
          if (ropeF) {
            float pv = __shfl_xor(v, 1, 64);
            if (dorope) {
              float ang = (float)pos[row & 2047] * fr;
              float sn, cs;
              __sincosf(ang, &sn, &cs);
              v = (col & 1) ? (pv * sn + v * cs) : (v * cs - pv * sn);
            }
          }
          if (scaleF) v *= 0.12751743f;
          ((short*)sg.outp)[(size_t)row * sg.ldo + sg.ocol + col] = f2bf(v);
        }
      }
    }
  };

  stageB(0, Bt[0]);
  __syncthreads();  // drains A + B0
  for (int t = 0; t < 4; t++) {
    if (t) __syncthreads();  // drains B[t] DMA
    if (t + 1 < 4) stageB(t + 1, Bt[(t + 1) & 1]);  // overlaps comp+epi below
    comp(Bt[t & 1]);
    epi(bnu + t * 64);
#pragma unroll
    for (int mi = 0; mi < 4; mi++)
#pragma unroll
      for (int ni = 0; ni < 2; ni++) acc[mi][ni] = z;
  }
}

// ---------- causal flash attention: 128-q blocks, 32 q/wave, no-max softmax ----
// grid 768 (1-D, global LPT order), 256 thr. KVBLK=64 (R3/R7/R8-verified 85us).
__global__ __launch_bounds__(256, 2) void mla_attn(const short* __restrict__ Q,
                                                   const short* __restrict__ K,
                                                   const short* __restrict__ Vt,
                                                   short* __restrict__ O) {
  const int ld = 1536, SEQ = 2048;
  int tid = threadIdx.x, w = tid >> 6, lane = tid & 63;
  int quad = lane >> 4, l16 = lane & 15;
  int o = (int)blockIdx.x;
  int rank = o / 48;
  int g = o - rank * 48;
  int qt = (15 - rank) * 128;
  int hh = g % 12, b = g / 12;
  int qw = qt + w * 32;

  __shared__ short Kt[2][64 * 128];
  __shared__ short Vl[2][128 * 64];
  __shared__ short Pm[4][32 * 64];
  char* pwB = (char*)Pm[w];

  int kgo[4], vgo[4];
#pragma unroll
  for (int j = 0; j < 4; j++) {
    int rk = (w * 4 + j) * 4 + (lane >> 4);
    kgo[j] = rk * ld + (((lane & 15) ^ (rk & 7)) << 3);
    int rv = (w * 4 + j) * 8 + (lane >> 3);
    vgo[j] = rv * SEQ + (((lane & 7) ^ (rv & 7)) << 3);
  }
  const short* Kg = K + (size_t)b * SEQ * ld + hh * 128;
  const short* Vg = Vt + (size_t)(b * 12 + hh) * 128 * SEQ;

  short8 qf[2][4];
  {
    const short* Qg = Q + (size_t)(b * SEQ + qw + l16) * ld + hh * 128 + quad * 8;
#pragma unroll
    for (int nf = 0; nf < 2; nf++)
#pragma unroll
      for (int ks = 0; ks < 4; ks++)
        qf[nf][ks] = *(const short8*)(Qg + (size_t)nf * 16 * ld + ks * 32);
  }

  // ---- loop-invariant LDS byte offsets ----
  int koff[4][4], voff[2][8], pfo[2][2], pwo[2][4];
#pragma unroll
  for (int ks = 0; ks < 4; ks++)
#pragma unroll
    for (int mf = 0; mf < 4; mf++) {
      int row = mf * 16 + l16;
      koff[ks][mf] = row * 256 + ((((ks << 2) + quad) ^ (row & 7)) << 4);
    }
#pragma unroll
  for (int t = 0; t < 2; t++) {
#pragma unroll
    for (int df = 0; df < 8; df++) {
      int vr = df * 16 + l16;
      voff[t][df] = vr * 128 + ((((t << 2) + quad) ^ (vr & 7)) << 4);
    }
#pragma unroll
    for (int mq = 0; mq < 2; mq++)
      pfo[t][mq] = (mq * 16 + l16) * 128 + ((((t << 2) + quad) ^ (l16 & 7)) << 4);
#pragma unroll
    for (int mf = 0; mf < 4; mf++) {
      int p = (mf * 2 + (quad >> 1)) ^ (l16 & 7);
      pwo[t][mf] = (t * 16 + l16) * 128 + (p << 4) + ((quad & 1) << 3);
    }
  }

  float4v z = {0.f, 0.f, 0.f, 0.f};
  float4v oacc[2][8];
#pragma unroll
  for (int mq = 0; mq < 2; mq++)
#pragma unroll
    for (int df = 0; df < 8; df++) oacc[mq][df] = z;
  float l_i[2] = {0.f, 0.f};

#pragma unroll
  for (int j = 0; j < 4; j++) glds16(Kg + kgo[j], &Kt[0][(w * 4 + j) * 512]);
#pragma unroll
  for (int j = 0; j < 4; j++) glds16(Vg + vgo[j], &Vl[0][(w * 4 + j) * 512]);

  int ntiles = (qt >> 6) + 2;  // always even

#define ATTN_TILE(IT, NB, NB1)                                                 \
  do {                                                                         \
    int kt = (IT) << 6;                                                        \
    __syncthreads();                                                           \
    if ((IT) + 1 < ntiles) {                                                   \
      const short* kn = Kg + (size_t)(kt + 64) * ld;                           \
      const short* vn = Vg + (kt + 64);                                        \
      _Pragma("unroll") for (int j = 0; j < 4; j++)                            \
          glds16(kn + kgo[j], &Kt[NB1][(w * 4 + j) * 512]);                    \
      _Pragma("unroll") for (int j = 0; j < 4; j++)                            \
          glds16(vn + vgo[j], &Vl[NB1][(w * 4 + j) * 512]);                    \
    }                                                                          \
    if (kt <= qw + 31) {                                                       \
      const char* Kb = (const char*)Kt[NB];                                    \
      const char* Vb = (const char*)Vl[NB];                                    \
      float4v sf[4][2];                                                        \
      __builtin_amdgcn_s_setprio(1);                                           \
      _Pragma("unroll") for (int mf = 0; mf < 4; mf++) {                       \
        short8 a = *(const short8*)(Kb + koff[0][mf]);                         \
        sf[mf][0] = MFMA16(a, qf[0][0], z);                                    \
        sf[mf][1] = MFMA16(a, qf[1][0], z);                                    \
      }                                                                        \
      _Pragma("unroll") for (int ks = 1; ks < 4; ks++) {                       \
        _Pragma("unroll") for (int mf = 0; mf < 4; mf++) {                     \
          short8 a = *(const short8*)(Kb + koff[ks][mf]);                      \
          sf[mf][0] = MFMA16(a, qf[0][ks], sf[mf][0]);                         \
          sf[mf][1] = MFMA16(a, qf[1][ks], sf[mf][1]);                         \
        }                                                                      \
      }                                                                        \
      __builtin_amdgcn_s_setprio(0);                                           \
      if (kt + 63 > qw) {                                                      \
        _Pragma("unroll") for (int mf = 0; mf < 4; mf++) {                     \
          int key = kt + mf * 16 + quad * 4;                                   \
          _Pragma("unroll") for (int nf = 0; nf < 2; nf++) {                   \
            int q = qw + nf * 16 + l16;                                        \
            _Pragma("unroll") for (int r = 0; r < 4; r++)                      \
                if (key + r > q) sf[mf][nf][r] = -3e38f;                       \
          }                                                                    \
        }                                                                      \
      }                                                                        \
      _Pragma("unroll") for (int nf = 0; nf < 2; nf++) {                       \
        float ps = 0.f;                                                        \
        _Pragma("unroll") for (int mf = 0; mf < 4; mf++)                       \
            _Pragma("unroll") for (int r = 0; r < 4; r++) {                    \
          float e = exp2f(sf[mf][nf][r]);                                      \
          sf[mf][nf][r] = e;                                                   \
          ps += e;                                                             \
        }                                                                      \
        l_i[nf] += ps;                                                         \
        _Pragma("unroll") for (int mf = 0; mf < 4; mf++) {                     \
          int2v pk;                                                            \
          pk[0] = cvtpk(sf[mf][nf][0], sf[mf][nf][1]);                         \
          pk[1] = cvtpk(sf[mf][nf][2], sf[mf][nf][3]);                         \
          *(int2v*)(pwB + pwo[nf][mf]) = pk;                                   \
        }                                                                      \
      }                                                                        \
      __builtin_amdgcn_s_setprio(1);                                           \
      _Pragma("unroll") for (int t = 0; t < 2; t++) {                          \
        short8 pf0 = *(const short8*)(pwB + pfo[t][0]);                        \
        short8 pf1 = *(const short8*)(pwB + pfo[t][1]);                        \
        _Pragma("unroll") for (int df = 0; df < 8; df++) {                     \
          short8 vf = *(const short8*)(Vb + voff[t][df]);                      \
          oacc[0][df] = MFMA16(pf0, vf, oacc[0][df]);                          \
          oacc[1][df] = MFMA16(pf1, vf, oacc[1][df]);                          \
        }                                                                      \
      }                                                                        \
      __builtin_amdgcn_s_setprio(0);                                           \
    }                                                                          \
  } while (0)

  for (int it = 0; it < ntiles; it += 2) {
    ATTN_TILE(it, 0, 1);
    ATTN_TILE(it + 1, 1, 0);
  }
#undef ATTN_TILE

  // ---- epilogue: reduce l across quads, scale, store ----
  short* Og = O + (size_t)(b * SEQ + qw) * ld + hh * 128;
#pragma unroll
  for (int mq = 0; mq < 2; mq++) {
    float l = l_i[mq];
    l += __shfl_xor(l, 16, 64);
    l += __shfl_xor(l, 32, 64);
    float linv = 1.0f / l;
    float lb[4];
#pragma unroll
    for (int r = 0; r < 4; r++) lb[r] = __shfl(linv, (quad << 2) + r, 64);
#pragma unroll
    for (int df = 0; df < 8; df++)
#pragma unroll
      for (int r = 0; r < 4; r++)
        Og[(size_t)(mq * 16 + (quad << 2) + r) * ld + df * 16 + l16] =
            f2bf(oacc[mq][df][r] * lb[r]);
  }
}

// ---------- launcher ----------
extern "C" void kernel_launch(void* const* d_in, const int* in_sizes, int n_in,
                              void* d_out, int out_size, void* d_ws, size_t ws_size,
                              hipStream_t stream) {
  const int S = 2048, DM = 768, DL = 128, HD = 1536;
  const int M = 4 * S;  // 8192
  const int BIG = 1 << 28;

  const float* x = (const float*)d_in[0];
  const int* pos = (const int*)d_in[1];
  const float* W_dkv = (const float*)d_in[2];
  const float* b_dkv = (const float*)d_in[3];
  const float* W_dq = (const float*)d_in[4];
  const float* b_dq = (const float*)d_in[5];
  const float* W_uk_nope = (const float*)d_in[6];
  const float* b_uk_nope = (const float*)d_in[7];
  const float* W_uv = (const float*)d_in[8];
  const float* b_uv = (const float*)d_in[9];
  const float* W_uq_nope = (const float*)d_in[10];
  const float* b_uq_nope = (const float*)d_in[11];
  const float* W_uq_rope = (const float*)d_in[12];
  const float* b_uq_rope = (const float*)d_in[13];
  const float* W_uk_rope = (const float*)d_in[14];
  const float* b_uk_rope = (const float*)d_in[15];
  const float* W_o = (const float*)d_in[16];
  const float* b_o = (const float*)d_in[17];

  char* p = (char*)d_ws;
  size_t off = 0;
  auto take = [&](size_t nelem) -> short* {
    short* r = (short*)(p + off);
    off += (nelem * 2 + 255) & ~(size_t)255;
    return r;
  };
  short* xb = take((size_t)M * DM);
  short* Wdq = take(DL * DM);
  short* Wdkv = take(DL * DM);
  short* Wuqnope = take(768 * DL);
  short* Wuqrope = take(768 * DL);
  short* Wuknope = take(768 * DL);
  short* Wuv = take(1536 * DL);
  short* Wukrope = take(768 * DM);
  short* Wo = take(768 * 1536);
  short* Cm = take((size_t)M * 256);  // [C_q | C_kv]
  short* Qm = take((size_t)M * HD);
  short* Km = take((size_t)M * HD);
  short* Vtm = take((size_t)M * HD);  // V^T: [b][h*128+d][s]
  short* Om = take((size_t)M * HD);
  if (off > ws_size) return;

  CastArgs ca;
  const float* srcs[9] = {x, W_dq, W_dkv, W_uq_nope, W_uq_rope, W_uk_nope, W_uv, W_uk_rope, W_o};
  short* dsts[9] = {xb, Wdq, Wdkv, Wuqnope, Wuqrope, Wuknope, Wuv, Wukrope, Wo};
  int ns[9] = {M * DM, DL * DM, DL * DM, 768 * DL, 768 * DL, 768 * DL, 1536 * DL, 768 * DM, 768 * 1536};
  ca.start[0] = 0;
  for (int i = 0; i < 9; i++) {
    ca.seg[i].src = srcs[i];
    ca.seg[i].dst = dsts[i];
    ca.seg[i].n4 = ns[i] / 4;
    ca.start[i + 1] = ca.start[i] + (ca.seg[i].n4 + 255) / 256;
  }
  castk<<<dim3(ca.start[9]), dim3(256), 0, stream>>>(ca);

  // ---- launch 1: C (N=256,K=768) || rope(k_rope) (N=768,K=768) ----
  GArgs g1;
  g1.s[0].A = xb;   g1.s[0].W = Wdq;      g1.s[0].bias0 = b_dq;      g1.s[0].bias1 = b_dkv;
  g1.s[0].outp = Cm; g1.s[0].lda = DM; g1.s[0].ldw = DM; g1.s[0].bsplit = 128;
  g1.s[0].ropestart = 0; g1.s[0].ldo = 256; g1.s[0].ocol = 0; g1.s[0].K = DM; g1.s[0].flags = 0;
  g1.s[1].A = xb;   g1.s[1].W = Wukrope;  g1.s[1].bias0 = b_uk_rope; g1.s[1].bias1 = b_uk_rope;
  g1.s[1].outp = Km; g1.s[1].lda = DM; g1.s[1].ldw = DM; g1.s[1].bsplit = BIG;
  g1.s[1].ropestart = 0; g1.s[1].ldo = HD; g1.s[1].ocol = 768; g1.s[1].K = DM; g1.s[1].flags = 1;
  g1.s[2] = g1.s[1];
  g1.start[0] = 0; g1.start[1] = 2; g1.start[2] = 8; g1.start[3] = 8;
  gemm_c<<<dim3(M / 128, 8), dim3(256), 0, stream>>>(g1, pos);

  // ---- launch 2 (N-streaming thin-K): Q || k_nope || V^T ----
  GArgs g2;
  g2.s[0].A = Cm;   g2.s[0].W = Wuqnope;  g2.s[0].bias0 = b_uq_nope; g2.s[0].bias1 = b_uq_rope;
  g2.s[0].outp = Qm; g2.s[0].lda = 256; g2.s[0].ldw = DL; g2.s[0].bsplit = 768;
  g2.s[0].ropestart = 768; g2.s[0].ldo = HD; g2.s[0].ocol = 0; g2.s[0].K = DL;
  g2.s[0].flags = 1 | 2;
  g2.s[1].A = Cm + 128; g2.s[1].W = Wuknope; g2.s[1].bias0 = b_uk_nope; g2.s[1].bias1 = b_uk_nope;
  g2.s[1].outp = Km; g2.s[1].lda = 256; g2.s[1].ldw = DL; g2.s[1].bsplit = BIG;
  g2.s[1].ropestart = 0; g2.s[1].ldo = HD; g2.s[1].ocol = 0; g2.s[1].K = DL;
  g2.s[1].flags = 0;
  g2.s[2].A = Cm + 128; g2.s[2].W = Wuv;   g2.s[2].bias0 = b_uv;      g2.s[2].bias1 = b_uv;
  g2.s[2].outp = Vtm; g2.s[2].lda = 256; g2.s[2].ldw = DL; g2.s[2].bsplit = BIG;
  g2.s[2].ropestart = 0; g2.s[2].ldo = 0; g2.s[2].ocol = 0; g2.s[2].K = DL;
  g2.s[2].flags = 4;
  g2.start[0] = 0; g2.start[1] = 6; g2.start[2] = 9; g2.start[3] = 15;
  gemm_q<<<dim3(M / 128, 15), dim3(256), 0, stream>>>(g2, pos);

  // ---- attention: 768 blocks, global longest-first (LPT) order ----
  mla_attn<<<dim3(768), dim3(256), 0, stream>>>(Qm, Km, Vtm, Om);

  // ---- launch 3: out = O @ W_o^T + b_o (N=768, K=1536, fp32 out, 128x64 tiles) ----
  GArgs g3;
  g3.s[0].A = Om;   g3.s[0].W = Wo;       g3.s[0].bias0 = b_o;       g3.s[0].bias1 = b_o;
  g3.s[0].outp = d_out; g3.s[0].lda = HD; g3.s[0].ldw = HD; g3.s[0].bsplit = BIG;
  g3.s[0].ropestart = 0; g3.s[0].ldo = 768; g3.s[0].ocol = 0; g3.s[0].K = HD; g3.s[0].flags = 8;
  g3.s[1] = g3.s[0];
  g3.s[2] = g3.s[0];
  g3.start[0] = 0; g3.start[1] = 12; g3.start[2] = 12; g3.start[3] = 12;
  gemm_o<<<dim3(M / 128, 12), dim3(256), 0, stream>>>(g3, pos);
}

// Round 10
// 273.855 us; speedup vs baseline: 1.6004x; 1.0226x over previous
//
#include <hip/hip_runtime.h>

// ---------- types ----------
typedef __attribute__((ext_vector_type(8))) short short8;   // 8 x bf16
typedef __attribute__((ext_vector_type(4))) short short4v;  // 4 x bf16
typedef __attribute__((ext_vector_type(2))) int int2v;
typedef __attribute__((ext_vector_type(4))) float float4v;

#define MFMA16(a, b, c) __builtin_amdgcn_mfma_f32_16x16x32_bf16((a), (b), (c), 0, 0, 0)

__device__ __forceinline__ short f2bf(float f) {  // RNE fp32 -> bf16
  unsigned u = __float_as_uint(f);
  u += 0x7fffu + ((u >> 16) & 1u);
  return (short)(u >> 16);
}

// packed fp32x2 -> bf16x2 (RNE) in one VALU op
__device__ __forceinline__ int cvtpk(float a, float b) {
  int r;
  asm("v_cvt_pk_bf16_f32 %0, %1, %2" : "=v"(r) : "v"(a), "v"(b));
  return r;
}

// async global->LDS, 16B per lane; LDS dest = wave-uniform base + lane*16
__device__ __forceinline__ void glds16(const short* g, short* l) {
  __builtin_amdgcn_global_load_lds(
      (const __attribute__((address_space(1))) void*)g,
      (__attribute__((address_space(3))) void*)l, 16, 0, 0);
}

// ---------- fused fp32 -> bf16 cast (all 9 tensors, one launch) ----------
struct CastSeg { const float* src; short* dst; int n4; };
struct CastArgs { CastSeg seg[9]; int start[10]; };

__global__ __launch_bounds__(256) void castk(CastArgs a) {
  int blk = blockIdx.x;
  int si = 0;
#pragma unroll
  for (int i = 1; i < 9; i++) si += (blk >= a.start[i]);
  int i = (blk - a.start[si]) * 256 + threadIdx.x;
  if (i >= a.seg[si].n4) return;
  float4v f = ((const float4v*)a.seg[si].src)[i];
  short4v o;
  o[0] = f2bf(f[0]); o[1] = f2bf(f[1]); o[2] = f2bf(f[2]); o[3] = f2bf(f[3]);
  ((short4v*)a.seg[si].dst)[i] = o;
}

// ---------- shared structs ----------
// flags: 1=ROPE, 2=SCALE, 4=V^T out, 8=fp32 out
struct GSeg {
  const short* A;
  const short* W;
  const float* bias0;
  const float* bias1;
  void* outp;
  int lda, ldw, bsplit, ropestart, ldo, ocol, K, flags;
};
struct GArgs { GSeg s[3]; int start[4]; };

// ---------- gemm_c: fat-K 128x64 tiles, 48KB LDS -> 3 blocks/CU ----------
// Launch 1: C = x@[Wdq;Wdkv]^T (N=256, 4 units) || rope(k_rope) (N=768, 12
// units), K=768. Grid (64 m, 16) = 1024 blocks. Third application of the
// R9-proven lever: fat-K at 2 blk/CU is latency-bound; 128x64 + 48KB -> 3/CU.
__global__ __launch_bounds__(256, 3) void gemm_c(GArgs ga, const int* __restrict__ pos) {
  int by = blockIdx.y;
  int si = (by >= ga.start[1]) + (by >= ga.start[2]);
  const GSeg sg = ga.s[si];
  int tid = threadIdx.x, w = tid >> 6, lane = tid & 63;
  int quad = lane >> 4, l16 = lane & 15;
  bool ropeF = sg.flags & 1;
  int bm = blockIdx.x * 128, bn = (by - ga.start[si]) * 64;
  int wm = (w & 1) * 64, wn = (w >> 1) * 32;
  int lda = sg.lda, ldw = sg.ldw;

  __shared__ short At[2][128 * 64];  // 32KB
  __shared__ short Bt[2][64 * 64];   // 16KB

  int sra[4], sofa[4], srb[2], sofb[2];
#pragma unroll
  for (int j = 0; j < 4; j++) {
    int r = w * 32 + j * 8 + (lane >> 3);
    sra[j] = r;
    sofa[j] = ((lane & 7) ^ (r & 7)) << 3;
  }
#pragma unroll
  for (int j = 0; j < 2; j++) {
    int r = w * 16 + j * 8 + (lane >> 3);
    srb[j] = r;
    sofb[j] = ((lane & 7) ^ (r & 7)) << 3;
  }
  const short* Ag = sg.A + (size_t)bm * lda;
  const short* Wg = sg.W + (size_t)bn * ldw;

  float4v acc[4][2];
  float4v z = {0.f, 0.f, 0.f, 0.f};
#pragma unroll
  for (int mi = 0; mi < 4; mi++)
#pragma unroll
    for (int ni = 0; ni < 2; ni++) acc[mi][ni] = z;

  auto stage = [&](int kt, int nb) {
#pragma unroll
    for (int j = 0; j < 4; j++)
      glds16(Ag + (size_t)sra[j] * lda + kt + sofa[j], &At[nb][(w * 32 + j * 8) * 64]);
#pragma unroll
    for (int j = 0; j < 2; j++)
      glds16(Wg + (size_t)srb[j] * ldw + kt + sofb[j], &Bt[nb][(w * 16 + j * 8) * 64]);
  };

  auto comp = [&](const short* Ab, const short* Bb) {
#pragma unroll
    for (int ks = 0; ks < 2; ks++) {
      short8 af[4], bf[2];
#pragma unroll
      for (int mi = 0; mi < 4; mi++) {
        int row = wm + mi * 16 + l16;
        af[mi] = *(const short8*)&Ab[(row << 6) + ((((ks << 2) + quad) ^ (row & 7)) << 3)];
      }
#pragma unroll
      for (int ni = 0; ni < 2; ni++) {
        int row = wn + ni * 16 + l16;
        bf[ni] = *(const short8*)&Bb[(row << 6) + ((((ks << 2) + quad) ^ (row & 7)) << 3)];
      }
#pragma unroll
      for (int mi = 0; mi < 4; mi++)
#pragma unroll
        for (int ni = 0; ni < 2; ni++)
          acc[mi][ni] = MFMA16(af[mi], bf[ni], acc[mi][ni]);
    }
  };

  int nk = sg.K >> 6;  // 12
  stage(0, 0);
  for (int it = 0; it < nk; it++) {
    __syncthreads();
    if (it + 1 < nk) stage((it + 1) << 6, (it + 1) & 1);
    comp(At[it & 1], Bt[it & 1]);
  }

  // ---- epilogue: bias + optional rope, bf16 out ----
#pragma unroll
  for (int ni = 0; ni < 2; ni++) {
    int col = bn + wn + ni * 16 + l16;
    float bv = (col < sg.bsplit) ? sg.bias0[col] : sg.bias1[col - sg.bsplit];
    float fr = 0.f;
    bool dorope = ropeF && (col >= sg.ropestart);
    if (dorope) {
      int ri = (col - sg.ropestart) & ~1;
      fr = exp2f((float)ri * (-13.287712379549449f / 768.0f));
    }
#pragma unroll
    for (int mi = 0; mi < 4; mi++) {
      int row0 = bm + wm + mi * 16 + quad * 4;
#pragma unroll
      for (int r = 0; r < 4; r++) {
        int row = row0 + r;
        float v = acc[mi][ni][r] + bv;
        if (ropeF) {
          float pv = __shfl_xor(v, 1, 64);
          if (dorope) {
            float ang = (float)pos[row & 2047] * fr;
            float sn, cs;
            __sincosf(ang, &sn, &cs);
            v = (col & 1) ? (pv * sn + v * cs) : (v * cs - pv * sn);
          }
        }
        ((short*)sg.outp)[(size_t)row * sg.ldo + sg.ocol + col] = f2bf(v);
      }
    }
  }
}

// ---------- gemm_o: fat-K 128x64 tiles, 48KB LDS -> 3 blocks/CU (R9) ----------
__global__ __launch_bounds__(256, 3) void gemm_o(GArgs ga, const int* __restrict__ pos) {
  const GSeg sg = ga.s[0];
  int tid = threadIdx.x, w = tid >> 6, lane = tid & 63;
  int quad = lane >> 4, l16 = lane & 15;
  int bm = blockIdx.x * 128, bn = blockIdx.y * 64;
  int wm = (w & 1) * 64, wn = (w >> 1) * 32;
  int lda = sg.lda, ldw = sg.ldw;

  __shared__ short At[2][128 * 64];  // 32KB
  __shared__ short Bt[2][64 * 64];   // 16KB

  int sra[4], sofa[4], srb[2], sofb[2];
#pragma unroll
  for (int j = 0; j < 4; j++) {
    int r = w * 32 + j * 8 + (lane >> 3);
    sra[j] = r;
    sofa[j] = ((lane & 7) ^ (r & 7)) << 3;
  }
#pragma unroll
  for (int j = 0; j < 2; j++) {
    int r = w * 16 + j * 8 + (lane >> 3);
    srb[j] = r;
    sofb[j] = ((lane & 7) ^ (r & 7)) << 3;
  }
  const short* Ag = sg.A + (size_t)bm * lda;
  const short* Wg = sg.W + (size_t)bn * ldw;

  float4v acc[4][2];
  float4v z = {0.f, 0.f, 0.f, 0.f};
#pragma unroll
  for (int mi = 0; mi < 4; mi++)
#pragma unroll
    for (int ni = 0; ni < 2; ni++) acc[mi][ni] = z;

  auto stage = [&](int kt, int nb) {
#pragma unroll
    for (int j = 0; j < 4; j++)
      glds16(Ag + (size_t)sra[j] * lda + kt + sofa[j], &At[nb][(w * 32 + j * 8) * 64]);
#pragma unroll
    for (int j = 0; j < 2; j++)
      glds16(Wg + (size_t)srb[j] * ldw + kt + sofb[j], &Bt[nb][(w * 16 + j * 8) * 64]);
  };

  auto comp = [&](const short* Ab, const short* Bb) {
#pragma unroll
    for (int ks = 0; ks < 2; ks++) {
      short8 af[4], bf[2];
#pragma unroll
      for (int mi = 0; mi < 4; mi++) {
        int row = wm + mi * 16 + l16;
        af[mi] = *(const short8*)&Ab[(row << 6) + ((((ks << 2) + quad) ^ (row & 7)) << 3)];
      }
#pragma unroll
      for (int ni = 0; ni < 2; ni++) {
        int row = wn + ni * 16 + l16;
        bf[ni] = *(const short8*)&Bb[(row << 6) + ((((ks << 2) + quad) ^ (row & 7)) << 3)];
      }
#pragma unroll
      for (int mi = 0; mi < 4; mi++)
#pragma unroll
        for (int ni = 0; ni < 2; ni++)
          acc[mi][ni] = MFMA16(af[mi], bf[ni], acc[mi][ni]);
    }
  };

  int nk = sg.K >> 6;  // 24
  stage(0, 0);
  for (int it = 0; it < nk; it++) {
    __syncthreads();
    if (it + 1 < nk) stage((it + 1) << 6, (it + 1) & 1);
    comp(At[it & 1], Bt[it & 1]);
  }
  // fp32 epilogue
#pragma unroll
  for (int ni = 0; ni < 2; ni++) {
    int col = bn + wn + ni * 16 + l16;
    float bv = sg.bias0[col];
#pragma unroll
    for (int mi = 0; mi < 4; mi++) {
      int row0 = bm + wm + mi * 16 + quad * 4;
#pragma unroll
      for (int r = 0; r < 4; r++)
        ((float*)sg.outp)[(size_t)(row0 + r) * sg.ldo + col] = acc[mi][ni][r] + bv;
    }
  }
}

// ---------- thin-K (K=128) N-streaming GEMM: Q || k_nope || V^T (R8) ----------
__global__ __launch_bounds__(256, 2) void gemm_q(GArgs ga, const int* __restrict__ pos) {
  int by = blockIdx.y;
  int si = (by >= ga.start[1]) + (by >= ga.start[2]);
  const GSeg sg = ga.s[si];
  int tid = threadIdx.x, w = tid >> 6, lane = tid & 63;
  int quad = lane >> 4, l16 = lane & 15;
  bool ropeF = sg.flags & 1, scaleF = sg.flags & 2, vtF = sg.flags & 4;
  int bm = blockIdx.x * 128;
  int bnu = (by - ga.start[si]) * 256;  // segment-local unit base
  int wm = (w & 1) * 64, wn = (w >> 1) * 32;

  __shared__ short At[128 * 128];    // 32KB: 128 rows x K=128
  __shared__ short Bt[2][64 * 128];  // 2x16KB W subtiles
  __shared__ short Tt[64 * 128];     // 16KB transpose scratch (V^T)

  // ---- stage A once: 128 rows x 256B, attention-style XOR chunk swizzle ----
  const short* Ag = sg.A + (size_t)bm * 256;
#pragma unroll
  for (int j = 0; j < 8; j++) {
    int rk = w * 32 + j * 4 + (lane >> 4);
    glds16(Ag + (size_t)rk * 256 + ((l16 ^ (rk & 7)) << 3),
           &At[(w * 32 + j * 4) * 128]);
  }
  const short* Wg0 = sg.W + (size_t)bnu * 128;
  auto stageB = [&](int sub, short* dst) {
    const short* Wg = Wg0 + (size_t)(sub * 64) * 128;
#pragma unroll
    for (int j = 0; j < 4; j++) {
      int rk = w * 16 + j * 4 + (lane >> 4);
      glds16(Wg + (size_t)rk * 128 + ((l16 ^ (rk & 7)) << 3),
             &dst[(w * 16 + j * 4) * 128]);
    }
  };

  float4v acc[4][2];
  float4v z = {0.f, 0.f, 0.f, 0.f};
#pragma unroll
  for (int mi = 0; mi < 4; mi++)
#pragma unroll
    for (int ni = 0; ni < 2; ni++) acc[mi][ni] = z;

  auto comp = [&](const short* Bb) {
#pragma unroll
    for (int ks = 0; ks < 4; ks++) {
      short8 af[4], bf[2];
#pragma unroll
      for (int mi = 0; mi < 4; mi++) {
        int row = wm + mi * 16 + l16;
        af[mi] = *(const short8*)&At[(row << 7) + (((ks * 4 + quad) ^ (row & 7)) << 3)];
      }
#pragma unroll
      for (int ni = 0; ni < 2; ni++) {
        int row = wn + ni * 16 + l16;
        bf[ni] = *(const short8*)&Bb[(row << 7) + (((ks * 4 + quad) ^ (row & 7)) << 3)];
      }
#pragma unroll
      for (int mi = 0; mi < 4; mi++)
#pragma unroll
        for (int ni = 0; ni < 2; ni++)
          acc[mi][ni] = MFMA16(af[mi], bf[ni], acc[mi][ni]);
    }
  };

  auto epi = [&](int bnX) {  // bnX = segment-local col base of this 64-subtile
    if (vtF) {
      __syncthreads();  // prior Tt readers done
#pragma unroll
      for (int ni = 0; ni < 2; ni++) {
        int col = wn + ni * 16 + l16;  // [0,64)
        float bv = sg.bias0[bnX + col];
#pragma unroll
        for (int mi = 0; mi < 4; mi++) {
          int row0 = wm + mi * 16 + quad * 4;
          int rr = (row0 + ((col & 15) << 3)) & 127;
          short4v ov;
#pragma unroll
          for (int r = 0; r < 4; r++) ov[r] = f2bf(acc[mi][ni][r] + bv);
          *(short4v*)&Tt[col * 128 + rr] = ov;
        }
      }
      __syncthreads();
      int bidx = bm >> 11, s0 = bm & 2047;
      int sc = tid & 15;
#pragma unroll
      for (int cc = 0; cc < 4; cc++) {
        int c = cc * 16 + (tid >> 4);
        int rr = ((sc + (c & 15)) << 3) & 127;
        short8 v = *(const short8*)&Tt[c * 128 + rr];
        *(short8*)((short*)sg.outp + ((size_t)(bidx * 1536 + bnX + c)) * 2048 +
                   s0 + (sc << 3)) = v;
      }
      return;
    }
#pragma unroll
    for (int ni = 0; ni < 2; ni++) {
      int col = bnX + wn + ni * 16 + l16;
      float bv = (col < sg.bsplit) ? sg.bias0[col] : sg.bias1[col - sg.bsplit];
      float fr = 0.f;
      bool dorope = ropeF && (col >= sg.ropestart);
      if (dorope) {
        int ri = (col - sg.ropestart) & ~1;
        fr = exp2f((float)ri * (-13.287712379549449f / 768.0f));
      }
#pragma unroll
      for (int mi = 0; mi < 4; mi++) {
        int row0 = bm + wm + mi * 16 + quad * 4;
#pragma unroll
        for (int r = 0; r < 4; r++) {
          int row = row0 + r;
          float v = acc[mi][ni][r] + bv;
          if (ropeF) {
            float pv = __shfl_xor(v, 1, 64);
            if (dorope) {
              float ang = (float)pos[row & 2047] * fr;
              float sn, cs;
              __sincosf(ang, &sn, &cs);
              v = (col & 1) ? (pv * sn + v * cs) : (v * cs - pv * sn);
            }
          }
          if (scaleF) v *= 0.12751743f;
          ((short*)sg.outp)[(size_t)row * sg.ldo + sg.ocol + col] = f2bf(v);
        }
      }
    }
  };

  stageB(0, Bt[0]);
  __syncthreads();  // drains A + B0
  for (int t = 0; t < 4; t++) {
    if (t) __syncthreads();  // drains B[t] DMA
    if (t + 1 < 4) stageB(t + 1, Bt[(t + 1) & 1]);  // overlaps comp+epi below
    comp(Bt[t & 1]);
    epi(bnu + t * 64);
#pragma unroll
    for (int mi = 0; mi < 4; mi++)
#pragma unroll
      for (int ni = 0; ni < 2; ni++) acc[mi][ni] = z;
  }
}

// ---------- causal flash attention: 128-q blocks, 32 q/wave, no-max softmax ----
// grid 768 (1-D, global LPT order), 256 thr. KVBLK=64 (R3/R7/R8/R9 85us).
__global__ __launch_bounds__(256, 2) void mla_attn(const short* __restrict__ Q,
                                                   const short* __restrict__ K,
                                                   const short* __restrict__ Vt,
                                                   short* __restrict__ O) {
  const int ld = 1536, SEQ = 2048;
  int tid = threadIdx.x, w = tid >> 6, lane = tid & 63;
  int quad = lane >> 4, l16 = lane & 15;
  int o = (int)blockIdx.x;
  int rank = o / 48;
  int g = o - rank * 48;
  int qt = (15 - rank) * 128;
  int hh = g % 12, b = g / 12;
  int qw = qt + w * 32;

  __shared__ short Kt[2][64 * 128];
  __shared__ short Vl[2][128 * 64];
  __shared__ short Pm[4][32 * 64];
  char* pwB = (char*)Pm[w];

  int kgo[4], vgo[4];
#pragma unroll
  for (int j = 0; j < 4; j++) {
    int rk = (w * 4 + j) * 4 + (lane >> 4);
    kgo[j] = rk * ld + (((lane & 15) ^ (rk & 7)) << 3);
    int rv = (w * 4 + j) * 8 + (lane >> 3);
    vgo[j] = rv * SEQ + (((lane & 7) ^ (rv & 7)) << 3);
  }
  const short* Kg = K + (size_t)b * SEQ * ld + hh * 128;
  const short* Vg = Vt + (size_t)(b * 12 + hh) * 128 * SEQ;

  short8 qf[2][4];
  {
    const short* Qg = Q + (size_t)(b * SEQ + qw + l16) * ld + hh * 128 + quad * 8;
#pragma unroll
    for (int nf = 0; nf < 2; nf++)
#pragma unroll
      for (int ks = 0; ks < 4; ks++)
        qf[nf][ks] = *(const short8*)(Qg + (size_t)nf * 16 * ld + ks * 32);
  }

  // ---- loop-invariant LDS byte offsets ----
  int koff[4][4], voff[2][8], pfo[2][2], pwo[2][4];
#pragma unroll
  for (int ks = 0; ks < 4; ks++)
#pragma unroll
    for (int mf = 0; mf < 4; mf++) {
      int row = mf * 16 + l16;
      koff[ks][mf] = row * 256 + ((((ks << 2) + quad) ^ (row & 7)) << 4);
    }
#pragma unroll
  for (int t = 0; t < 2; t++) {
#pragma unroll
    for (int df = 0; df < 8; df++) {
      int vr = df * 16 + l16;
      voff[t][df] = vr * 128 + ((((t << 2) + quad) ^ (vr & 7)) << 4);
    }
#pragma unroll
    for (int mq = 0; mq < 2; mq++)
      pfo[t][mq] = (mq * 16 + l16) * 128 + ((((t << 2) + quad) ^ (l16 & 7)) << 4);
#pragma unroll
    for (int mf = 0; mf < 4; mf++) {
      int p = (mf * 2 + (quad >> 1)) ^ (l16 & 7);
      pwo[t][mf] = (t * 16 + l16) * 128 + (p << 4) + ((quad & 1) << 3);
    }
  }

  float4v z = {0.f, 0.f, 0.f, 0.f};
  float4v oacc[2][8];
#pragma unroll
  for (int mq = 0; mq < 2; mq++)
#pragma unroll
    for (int df = 0; df < 8; df++) oacc[mq][df] = z;
  float l_i[2] = {0.f, 0.f};

#pragma unroll
  for (int j = 0; j < 4; j++) glds16(Kg + kgo[j], &Kt[0][(w * 4 + j) * 512]);
#pragma unroll
  for (int j = 0; j < 4; j++) glds16(Vg + vgo[j], &Vl[0][(w * 4 + j) * 512]);

  int ntiles = (qt >> 6) + 2;  // always even

#define ATTN_TILE(IT, NB, NB1)                                                 \
  do {                                                                         \
    int kt = (IT) << 6;                                                        \
    __syncthreads();                                                           \
    if ((IT) + 1 < ntiles) {                                                   \
      const short* kn = Kg + (size_t)(kt + 64) * ld;                           \
      const short* vn = Vg + (kt + 64);                                        \
      _Pragma("unroll") for (int j = 0; j < 4; j++)                            \
          glds16(kn + kgo[j], &Kt[NB1][(w * 4 + j) * 512]);                    \
      _Pragma("unroll") for (int j = 0; j < 4; j++)                            \
          glds16(vn + vgo[j], &Vl[NB1][(w * 4 + j) * 512]);                    \
    }                                                                          \
    if (kt <= qw + 31) {                                                       \
      const char* Kb = (const char*)Kt[NB];                                    \
      const char* Vb = (const char*)Vl[NB];                                    \
      float4v sf[4][2];                                                        \
      __builtin_amdgcn_s_setprio(1);                                           \
      _Pragma("unroll") for (int mf = 0; mf < 4; mf++) {                       \
        short8 a = *(const short8*)(Kb + koff[0][mf]);                         \
        sf[mf][0] = MFMA16(a, qf[0][0], z);                                    \
        sf[mf][1] = MFMA16(a, qf[1][0], z);                                    \
      }                                                                        \
      _Pragma("unroll") for (int ks = 1; ks < 4; ks++) {                       \
        _Pragma("unroll") for (int mf = 0; mf < 4; mf++) {                     \
          short8 a = *(const short8*)(Kb + koff[ks][mf]);                      \
          sf[mf][0] = MFMA16(a, qf[0][ks], sf[mf][0]);                         \
          sf[mf][1] = MFMA16(a, qf[1][ks], sf[mf][1]);                         \
        }                                                                      \
      }                                                                        \
      __builtin_amdgcn_s_setprio(0);                                           \
      if (kt + 63 > qw) {                                                      \
        _Pragma("unroll") for (int mf = 0; mf < 4; mf++) {                     \
          int key = kt + mf * 16 + quad * 4;                                   \
          _Pragma("unroll") for (int nf = 0; nf < 2; nf++) {                   \
            int q = qw + nf * 16 + l16;                                        \
            _Pragma("unroll") for (int r = 0; r < 4; r++)                      \
                if (key + r > q) sf[mf][nf][r] = -3e38f;                       \
          }                                                                    \
        }                                                                      \
      }                                                                        \
      _Pragma("unroll") for (int nf = 0; nf < 2; nf++) {                       \
        float ps = 0.f;                                                        \
        _Pragma("unroll") for (int mf = 0; mf < 4; mf++)                       \
            _Pragma("unroll") for (int r = 0; r < 4; r++) {                    \
          float e = exp2f(sf[mf][nf][r]);                                      \
          sf[mf][nf][r] = e;                                                   \
          ps += e;                                                             \
        }                                                                      \
        l_i[nf] += ps;                                                         \
        _Pragma("unroll") for (int mf = 0; mf < 4; mf++) {                     \
          int2v pk;                                                            \
          pk[0] = cvtpk(sf[mf][nf][0], sf[mf][nf][1]);                         \
          pk[1] = cvtpk(sf[mf][nf][2], sf[mf][nf][3]);                         \
          *(int2v*)(pwB + pwo[nf][mf]) = pk;                                   \
        }                                                                      \
      }                                                                        \
      __builtin_amdgcn_s_setprio(1);                                           \
      _Pragma("unroll") for (int t = 0; t < 2; t++) {                          \
        short8 pf0 = *(const short8*)(pwB + pfo[t][0]);                        \
        short8 pf1 = *(const short8*)(pwB + pfo[t][1]);                        \
        _Pragma("unroll") for (int df = 0; df < 8; df++) {                     \
          short8 vf = *(const short8*)(Vb + voff[t][df]);                      \
          oacc[0][df] = MFMA16(pf0, vf, oacc[0][df]);                          \
          oacc[1][df] = MFMA16(pf1, vf, oacc[1][df]);                          \
        }                                                                      \
      }                                                                        \
      __builtin_amdgcn_s_setprio(0);                                           \
    }                                                                          \
  } while (0)

  for (int it = 0; it < ntiles; it += 2) {
    ATTN_TILE(it, 0, 1);
    ATTN_TILE(it + 1, 1, 0);
  }
#undef ATTN_TILE

  // ---- epilogue: reduce l across quads, scale, store ----
  short* Og = O + (size_t)(b * SEQ + qw) * ld + hh * 128;
#pragma unroll
  for (int mq = 0; mq < 2; mq++) {
    float l = l_i[mq];
    l += __shfl_xor(l, 16, 64);
    l += __shfl_xor(l, 32, 64);
    float linv = 1.0f / l;
    float lb[4];
#pragma unroll
    for (int r = 0; r < 4; r++) lb[r] = __shfl(linv, (quad << 2) + r, 64);
#pragma unroll
    for (int df = 0; df < 8; df++)
#pragma unroll
      for (int r = 0; r < 4; r++)
        Og[(size_t)(mq * 16 + (quad << 2) + r) * ld + df * 16 + l16] =
            f2bf(oacc[mq][df][r] * lb[r]);
  }
}

// ---------- launcher ----------
extern "C" void kernel_launch(void* const* d_in, const int* in_sizes, int n_in,
                              void* d_out, int out_size, void* d_ws, size_t ws_size,
                              hipStream_t stream) {
  const int S = 2048, DM = 768, DL = 128, HD = 1536;
  const int M = 4 * S;  // 8192
  const int BIG = 1 << 28;

  const float* x = (const float*)d_in[0];
  const int* pos = (const int*)d_in[1];
  const float* W_dkv = (const float*)d_in[2];
  const float* b_dkv = (const float*)d_in[3];
  const float* W_dq = (const float*)d_in[4];
  const float* b_dq = (const float*)d_in[5];
  const float* W_uk_nope = (const float*)d_in[6];
  const float* b_uk_nope = (const float*)d_in[7];
  const float* W_uv = (const float*)d_in[8];
  const float* b_uv = (const float*)d_in[9];
  const float* W_uq_nope = (const float*)d_in[10];
  const float* b_uq_nope = (const float*)d_in[11];
  const float* W_uq_rope = (const float*)d_in[12];
  const float* b_uq_rope = (const float*)d_in[13];
  const float* W_uk_rope = (const float*)d_in[14];
  const float* b_uk_rope = (const float*)d_in[15];
  const float* W_o = (const float*)d_in[16];
  const float* b_o = (const float*)d_in[17];

  char* p = (char*)d_ws;
  size_t off = 0;
  auto take = [&](size_t nelem) -> short* {
    short* r = (short*)(p + off);
    off += (nelem * 2 + 255) & ~(size_t)255;
    return r;
  };
  short* xb = take((size_t)M * DM);
  short* Wdq = take(DL * DM);
  short* Wdkv = take(DL * DM);
  short* Wuqnope = take(768 * DL);
  short* Wuqrope = take(768 * DL);
  short* Wuknope = take(768 * DL);
  short* Wuv = take(1536 * DL);
  short* Wukrope = take(768 * DM);
  short* Wo = take(768 * 1536);
  short* Cm = take((size_t)M * 256);  // [C_q | C_kv]
  short* Qm = take((size_t)M * HD);
  short* Km = take((size_t)M * HD);
  short* Vtm = take((size_t)M * HD);  // V^T: [b][h*128+d][s]
  short* Om = take((size_t)M * HD);
  if (off > ws_size) return;

  CastArgs ca;
  const float* srcs[9] = {x, W_dq, W_dkv, W_uq_nope, W_uq_rope, W_uk_nope, W_uv, W_uk_rope, W_o};
  short* dsts[9] = {xb, Wdq, Wdkv, Wuqnope, Wuqrope, Wuknope, Wuv, Wukrope, Wo};
  int ns[9] = {M * DM, DL * DM, DL * DM, 768 * DL, 768 * DL, 768 * DL, 1536 * DL, 768 * DM, 768 * 1536};
  ca.start[0] = 0;
  for (int i = 0; i < 9; i++) {
    ca.seg[i].src = srcs[i];
    ca.seg[i].dst = dsts[i];
    ca.seg[i].n4 = ns[i] / 4;
    ca.start[i + 1] = ca.start[i] + (ca.seg[i].n4 + 255) / 256;
  }
  castk<<<dim3(ca.start[9]), dim3(256), 0, stream>>>(ca);

  // ---- launch 1 (128x64, 3/CU): C (4 units) || rope(k_rope) (12 units), K=768 ----
  GArgs g1;
  g1.s[0].A = xb;   g1.s[0].W = Wdq;      g1.s[0].bias0 = b_dq;      g1.s[0].bias1 = b_dkv;
  g1.s[0].outp = Cm; g1.s[0].lda = DM; g1.s[0].ldw = DM; g1.s[0].bsplit = 128;
  g1.s[0].ropestart = 0; g1.s[0].ldo = 256; g1.s[0].ocol = 0; g1.s[0].K = DM; g1.s[0].flags = 0;
  g1.s[1].A = xb;   g1.s[1].W = Wukrope;  g1.s[1].bias0 = b_uk_rope; g1.s[1].bias1 = b_uk_rope;
  g1.s[1].outp = Km; g1.s[1].lda = DM; g1.s[1].ldw = DM; g1.s[1].bsplit = BIG;
  g1.s[1].ropestart = 0; g1.s[1].ldo = HD; g1.s[1].ocol = 768; g1.s[1].K = DM; g1.s[1].flags = 1;
  g1.s[2] = g1.s[1];
  g1.start[0] = 0; g1.start[1] = 4; g1.start[2] = 16; g1.start[3] = 16;
  gemm_c<<<dim3(M / 128, 16), dim3(256), 0, stream>>>(g1, pos);

  // ---- launch 2 (N-streaming thin-K): Q || k_nope || V^T ----
  GArgs g2;
  g2.s[0].A = Cm;   g2.s[0].W = Wuqnope;  g2.s[0].bias0 = b_uq_nope; g2.s[0].bias1 = b_uq_rope;
  g2.s[0].outp = Qm; g2.s[0].lda = 256; g2.s[0].ldw = DL; g2.s[0].bsplit = 768;
  g2.s[0].ropestart = 768; g2.s[0].ldo = HD; g2.s[0].ocol = 0; g2.s[0].K = DL;
  g2.s[0].flags = 1 | 2;
  g2.s[1].A = Cm + 128; g2.s[1].W = Wuknope; g2.s[1].bias0 = b_uk_nope; g2.s[1].bias1 = b_uk_nope;
  g2.s[1].outp = Km; g2.s[1].lda = 256; g2.s[1].ldw = DL; g2.s[1].bsplit = BIG;
  g2.s[1].ropestart = 0; g2.s[1].ldo = HD; g2.s[1].ocol = 0; g2.s[1].K = DL;
  g2.s[1].flags = 0;
  g2.s[2].A = Cm + 128; g2.s[2].W = Wuv;   g2.s[2].bias0 = b_uv;      g2.s[2].bias1 = b_uv;
  g2.s[2].outp = Vtm; g2.s[2].lda = 256; g2.s[2].ldw = DL; g2.s[2].bsplit = BIG;
  g2.s[2].ropestart = 0; g2.s[2].ldo = 0; g2.s[2].ocol = 0; g2.s[2].K = DL;
  g2.s[2].flags = 4;
  g2.start[0] = 0; g2.start[1] = 6; g2.start[2] = 9; g2.start[3] = 15;
  gemm_q<<<dim3(M / 128, 15), dim3(256), 0, stream>>>(g2, pos);

  // ---- attention: 768 blocks, global longest-first (LPT) order ----
  mla_attn<<<dim3(768), dim3(256), 0, stream>>>(Qm, Km, Vtm, Om);

  // ---- launch 3 (128x64, 3/CU): out = O @ W_o^T + b_o (K=1536, fp32) ----
  GArgs g3;
  g3.s[0].A = Om;   g3.s[0].W = Wo;       g3.s[0].bias0 = b_o;       g3.s[0].bias1 = b_o;
  g3.s[0].outp = d_out; g3.s[0].lda = HD; g3.s[0].ldw = HD; g3.s[0].bsplit = BIG;
  g3.s[0].ropestart = 0; g3.s[0].ldo = 768; g3.s[0].ocol = 0; g3.s[0].K = HD; g3.s[0].flags = 8;
  g3.s[1] = g3.s[0];
  g3.s[2] = g3.s[0];
  g3.start[0] = 0; g3.start[1] = 12; g3.start[2] = 12; g3.start[3] = 12;
  gemm_o<<<dim3(M / 128, 12), dim3(256), 0, stream>>>(g3, pos);
}